// Round 4
// baseline (4041.135 us; speedup 1.0000x reference)
//
#include <hip/hip_runtime.h>
#include <hip/hip_bf16.h>
#include <cstdio>

#define Bz 2
#define Sz 4096
#define Dz 1024
#define DIz 2048
#define DSz 16
#define DTRz 64
#define NE 8
#define Fz 1024
#define FSz 2048
#define Tz (Bz*Sz)            // 8192 tokens
#define NCHUNK 16
#define CLEN (Sz/NCHUNK)      // 256
#define NDH 1024              // d-half width
#define SLOTCAP 16896         // 264 tiles * 64

typedef __hip_bfloat16 bf16;
typedef short bf16x8 __attribute__((ext_vector_type(8)));
typedef float f32x4 __attribute__((ext_vector_type(4)));

#define MFMA(a,b,c) __builtin_amdgcn_mfma_f32_16x16x32_bf16(a,b,c,0,0,0)

__device__ __forceinline__ float b2f(bf16 v){ return __bfloat162float(v); }
__device__ __forceinline__ bf16  f2b(float v){ return __float2bfloat16(v); }
__device__ __forceinline__ float us2f(unsigned short u){
  union { unsigned int i; float f; } v; v.i = ((unsigned int)u) << 16; return v.f;
}
__device__ __forceinline__ float silu(float v){ return v / (1.f + __expf(-v)); }
__device__ __forceinline__ void split2(float v, bf16& h, bf16& l){ h = f2b(v); l = f2b(v - b2f(h)); }
__device__ __forceinline__ float rc(const bf16* __restrict__ h, const bf16* __restrict__ l, size_t i){
  return b2f(h[i]) + b2f(l[i]);
}

// ---------------- guard diagnostic ----------------
__global__ void k_fill(float* __restrict__ o, float v){ o[threadIdx.x] = v; }

// ---------------- weight conversion ----------------
__global__ __launch_bounds__(256) void k_f2bf(const float* __restrict__ s, bf16* __restrict__ d, int n){
  int i = (blockIdx.x * 256 + threadIdx.x) * 4;
  if (i + 3 < n) {
    float4 v = *(const float4*)(s + i);
    d[i] = f2b(v.x); d[i+1] = f2b(v.y); d[i+2] = f2b(v.z); d[i+3] = f2b(v.w);
  }
}
// f32 -> hi/lo split
__global__ __launch_bounds__(256) void k_split(const float* __restrict__ s, bf16* __restrict__ dh,
                                               bf16* __restrict__ dl, int n){
  int i = (blockIdx.x * 256 + threadIdx.x) * 4;
  if (i + 3 < n) {
    float4 v = *(const float4*)(s + i);
    split2(v.x, dh[i],   dl[i]);
    split2(v.y, dh[i+1], dl[i+1]);
    split2(v.z, dh[i+2], dl[i+2]);
    split2(v.w, dh[i+3], dl[i+3]);
  }
}
// x_proj [96,2048] -> padded [128,2048] hi/lo (pad rows = 0)
__global__ __launch_bounds__(256) void k_split_pad(const float* __restrict__ s, bf16* __restrict__ dh,
                                                   bf16* __restrict__ dl){
  int i = (blockIdx.x * 256 + threadIdx.x) * 4;      // over 128*2048
  int row = i >> 11;
  if (row < 96) {
    float4 v = *(const float4*)(s + i);
    split2(v.x, dh[i],   dl[i]);
    split2(v.y, dh[i+1], dl[i+1]);
    split2(v.z, dh[i+2], dl[i+2]);
    split2(v.w, dh[i+3], dl[i+3]);
  } else {
    bf16 z = f2b(0.f);
    dh[i]=z; dh[i+1]=z; dh[i+2]=z; dh[i+3]=z;
    dl[i]=z; dl[i+1]=z; dl[i+2]=z; dl[i+3]=z;
  }
}

__global__ void k_zero_counts(int* __restrict__ c){
  if (threadIdx.x < NE) c[threadIdx.x] = 0;
}

// ---------------- rmsnorm (f32 in). HL: hi/lo out; else single bf16 out ----------------
template<bool HL>
__global__ __launch_bounds__(256) void k_rmsnorm(const float* __restrict__ x, const float* __restrict__ w,
                                                 bf16* __restrict__ oh, bf16* __restrict__ ol){
  int row = blockIdx.x;
  const float* xr = x + (size_t)row * Dz;
  int c4 = threadIdx.x * 4;
  float4 v = *(const float4*)(xr + c4);
  float ss = v.x*v.x + v.y*v.y + v.z*v.z + v.w*v.w;
  #pragma unroll
  for (int o = 32; o; o >>= 1) ss += __shfl_xor(ss, o);
  __shared__ float sred[4];
  if ((threadIdx.x & 63) == 0) sred[threadIdx.x >> 6] = ss;
  __syncthreads();
  float tot = sred[0] + sred[1] + sred[2] + sred[3];
  float sc = rsqrtf(tot * (1.f / Dz) + 1e-6f);
  float4 wv = *(const float4*)(w + c4);
  float o0 = v.x*sc*wv.x, o1 = v.y*sc*wv.y, o2 = v.z*sc*wv.z, o3 = v.w*sc*wv.w;
  size_t ci = (size_t)row * Dz + c4;
  if (HL) {
    split2(o0, oh[ci], ol[ci]);   split2(o1, oh[ci+1], ol[ci+1]);
    split2(o2, oh[ci+2], ol[ci+2]); split2(o3, oh[ci+3], ol[ci+3]);
  } else {
    oh[ci] = f2b(o0); oh[ci+1] = f2b(o1); oh[ci+2] = f2b(o2); oh[ci+3] = f2b(o3);
  }
}

// ---------------- split-precision GEMM: C = (Ah+Al)(Bh+Bl)^T, 3-term MFMA ----------------
// EPI: 0 = hi/lo store (C1h/C1l, ldc)
//      1 = in_proj dual: col<2048 -> C1h/C1l else C2h/C2l (inner ld 2048)
//      2 = softplus(v + epi[col]) -> hi/lo (C1h/C1l, ldc)
//      3 = v + epi[row*ldc+col] -> f32 Cf
//      4 = Cf[row*ldc+col] += v   (f32 accumulate)
template<int EPI>
__global__ __launch_bounds__(256) void k_gemm_sp(
    const bf16* __restrict__ Ah, const bf16* __restrict__ Al, int lda,
    const bf16* __restrict__ Bh, const bf16* __restrict__ Bl, int ldb,
    bf16* __restrict__ C1h, bf16* __restrict__ C1l,
    bf16* __restrict__ C2h, bf16* __restrict__ C2l,
    float* __restrict__ Cf, int ldc, int K,
    const float* __restrict__ epi)
{
  int row0 = blockIdx.x * 64;
  int lane = threadIdx.x & 63, wid = threadIdx.x >> 6;
  int m0 = row0 + (wid >> 1) * 32;
  int n0 = blockIdx.y * 64 + (wid & 1) * 32;
  int lr = lane & 15, lk = (lane >> 4) * 8;
  const bf16 *pah0 = Ah + (size_t)(m0+lr)*lda + lk, *pah1 = pah0 + (size_t)16*lda;
  const bf16 *pal0 = Al + (size_t)(m0+lr)*lda + lk, *pal1 = pal0 + (size_t)16*lda;
  const bf16 *pbh0 = Bh + (size_t)(n0+lr)*ldb + lk, *pbh1 = pbh0 + (size_t)16*ldb;
  const bf16 *pbl0 = Bl + (size_t)(n0+lr)*ldb + lk, *pbl1 = pbl0 + (size_t)16*ldb;
  f32x4 a00 = {0.f,0.f,0.f,0.f}, a01 = a00, a10 = a00, a11 = a00;
  for (int k = 0; k < K; k += 32) {
    bf16x8 AH0 = *(const bf16x8*)pah0, AH1 = *(const bf16x8*)pah1;
    bf16x8 AL0 = *(const bf16x8*)pal0, AL1 = *(const bf16x8*)pal1;
    bf16x8 BH0 = *(const bf16x8*)pbh0, BH1 = *(const bf16x8*)pbh1;
    bf16x8 BL0 = *(const bf16x8*)pbl0, BL1 = *(const bf16x8*)pbl1;
    a00 = MFMA(AH0, BH0, a00); a00 = MFMA(AH0, BL0, a00); a00 = MFMA(AL0, BH0, a00);
    a01 = MFMA(AH0, BH1, a01); a01 = MFMA(AH0, BL1, a01); a01 = MFMA(AL0, BH1, a01);
    a10 = MFMA(AH1, BH0, a10); a10 = MFMA(AH1, BL0, a10); a10 = MFMA(AL1, BH0, a10);
    a11 = MFMA(AH1, BH1, a11); a11 = MFMA(AH1, BL1, a11); a11 = MFMA(AL1, BH1, a11);
    pah0 += 32; pah1 += 32; pal0 += 32; pal1 += 32;
    pbh0 += 32; pbh1 += 32; pbl0 += 32; pbl1 += 32;
  }
  int crow = (lane >> 4) * 4, ccol = lane & 15;
  f32x4 accs[2][2] = {{a00, a01}, {a10, a11}};
  #pragma unroll
  for (int mi = 0; mi < 2; ++mi)
  #pragma unroll
  for (int ni = 0; ni < 2; ++ni)
  #pragma unroll
  for (int r = 0; r < 4; ++r) {
    int row = m0 + mi * 16 + crow + r;
    int col = n0 + ni * 16 + ccol;
    float v = accs[mi][ni][r];
    if (EPI == 0) {
      size_t ci = (size_t)row * ldc + col;
      split2(v, C1h[ci], C1l[ci]);
    } else if (EPI == 1) {
      size_t ci = (size_t)row * 2048 + (col & 2047);
      bf16 hv, lv; split2(v, hv, lv);
      if (col < 2048) { C1h[ci] = hv; C1l[ci] = lv; }
      else            { C2h[ci] = hv; C2l[ci] = lv; }
    } else if (EPI == 2) {
      float t = v + epi[col];
      float sp = (t > 20.f) ? t : log1pf(expf(t));
      size_t ci = (size_t)row * ldc + col;
      split2(sp, C1h[ci], C1l[ci]);
    } else if (EPI == 3) {
      size_t ci = (size_t)row * ldc + col;
      Cf[ci] = v + epi[ci];
    } else if (EPI == 4) {
      size_t ci = (size_t)row * ldc + col;
      Cf[ci] += v;
    }
  }
}

// ---------------- plain bf16 GEMM (MoE): C[M,N] = epi(A @ B^T) ----------------
// EPI: 4 = v*wslot[row] -> bf16, 5 = f32 accumulate (out += v)
template<int EPI, bool ROUTED>
__global__ __launch_bounds__(256) void k_gemm_bt(
    const bf16* __restrict__ A, int lda,
    const bf16* __restrict__ Bw, int ldb, size_t estride,
    void* __restrict__ Cp, int ldc, int K,
    const float* __restrict__ epi,
    const int* __restrict__ offs)
{
  int row0 = 0, e = 0;
  if (ROUTED) {
    int bid = blockIdx.x, cum = 0; e = -1;
    #pragma unroll
    for (int i = 0; i < 8; ++i) {
      int tiles = (offs[i+1] - offs[i]) >> 6;
      if (e < 0 && bid < cum + tiles) { e = i; row0 = offs[i] + ((bid - cum) << 6); }
      cum += tiles;
    }
    if (e < 0) return;
  } else {
    row0 = blockIdx.x * 64;
  }
  const bf16* Bm = Bw + (size_t)e * estride;
  int lane = threadIdx.x & 63, wid = threadIdx.x >> 6;
  int m0 = row0 + (wid >> 1) * 32;
  int n0 = blockIdx.y * 64 + (wid & 1) * 32;
  int lr = lane & 15, lk = (lane >> 4) * 8;
  const bf16* pa0 = A + (size_t)(m0 + lr) * lda + lk;
  const bf16* pa1 = pa0 + (size_t)16 * lda;
  const bf16* pb0 = Bm + (size_t)(n0 + lr) * ldb + lk;
  const bf16* pb1 = pb0 + (size_t)16 * ldb;
  f32x4 a00 = {0.f,0.f,0.f,0.f}, a01 = a00, a10 = a00, a11 = a00;
  for (int k = 0; k < K; k += 32) {
    bf16x8 va0 = *(const bf16x8*)pa0;
    bf16x8 va1 = *(const bf16x8*)pa1;
    bf16x8 vb0 = *(const bf16x8*)pb0;
    bf16x8 vb1 = *(const bf16x8*)pb1;
    a00 = MFMA(va0, vb0, a00);
    a01 = MFMA(va0, vb1, a01);
    a10 = MFMA(va1, vb0, a10);
    a11 = MFMA(va1, vb1, a11);
    pa0 += 32; pa1 += 32; pb0 += 32; pb1 += 32;
  }
  int crow = (lane >> 4) * 4, ccol = lane & 15;
  f32x4 accs[2][2] = {{a00, a01}, {a10, a11}};
  #pragma unroll
  for (int mi = 0; mi < 2; ++mi)
  #pragma unroll
  for (int ni = 0; ni < 2; ++ni)
  #pragma unroll
  for (int r = 0; r < 4; ++r) {
    int row = m0 + mi * 16 + crow + r;
    int col = n0 + ni * 16 + ccol;
    size_t ci = (size_t)row * ldc + col;
    float v = accs[mi][ni][r];
    if (EPI == 4) ((bf16*)Cp)[ci] = f2b(v * epi[row]);
    else if (EPI == 5) ((float*)Cp)[ci] += v;
  }
}

// ---------------- GLU GEMM: H = silu(A@Wg^T) * (A@Wu^T), optional row-gather ----------------
template<bool ROUTED>
__global__ __launch_bounds__(256) void k_glu(
    const bf16* __restrict__ A, int lda,
    const bf16* __restrict__ Wg, const bf16* __restrict__ Wu, int ldb, size_t estride,
    bf16* __restrict__ H, int ldc, int K,
    const int* __restrict__ offs, const int* __restrict__ toks,
    const int* __restrict__ counts)
{
  int row0 = 0, e = 0;
  if (ROUTED) {
    int bid = blockIdx.x, cum = 0; e = -1;
    #pragma unroll
    for (int i = 0; i < 8; ++i) {
      int tiles = (offs[i+1] - offs[i]) >> 6;
      if (e < 0 && bid < cum + tiles) { e = i; row0 = offs[i] + ((bid - cum) << 6); }
      cum += tiles;
    }
    if (e < 0) return;
  } else {
    row0 = blockIdx.x * 64;
  }
  int lane = threadIdx.x & 63, wid = threadIdx.x >> 6;
  int m0 = row0 + (wid >> 1) * 32;
  int n0 = blockIdx.y * 64 + (wid & 1) * 32;
  int lr = lane & 15, lk = (lane >> 4) * 8;
  int r0 = m0 + lr, r1 = r0 + 16;
  size_t ar0, ar1;
  if (ROUTED) {
    int base_e = offs[e], cnt = counts[e];
    int t0 = (r0 - base_e < cnt) ? toks[r0] : 0;   // padded slots never read toks
    int t1 = (r1 - base_e < cnt) ? toks[r1] : 0;
    ar0 = (size_t)t0 * lda; ar1 = (size_t)t1 * lda;
  } else {
    ar0 = (size_t)r0 * lda; ar1 = (size_t)r1 * lda;
  }
  const bf16* pa0 = A + ar0 + lk;
  const bf16* pa1 = A + ar1 + lk;
  const bf16* wg = Wg + (size_t)e * estride;
  const bf16* wu = Wu + (size_t)e * estride;
  const bf16* pg0 = wg + (size_t)(n0 + lr) * ldb + lk;
  const bf16* pg1 = pg0 + (size_t)16 * ldb;
  const bf16* pu0 = wu + (size_t)(n0 + lr) * ldb + lk;
  const bf16* pu1 = pu0 + (size_t)16 * ldb;
  f32x4 g00 = {0.f,0.f,0.f,0.f}, g01 = g00, g10 = g00, g11 = g00;
  f32x4 u00 = g00, u01 = g00, u10 = g00, u11 = g00;
  for (int k = 0; k < K; k += 32) {
    bf16x8 va0 = *(const bf16x8*)pa0;
    bf16x8 va1 = *(const bf16x8*)pa1;
    bf16x8 vg0 = *(const bf16x8*)pg0;
    bf16x8 vg1 = *(const bf16x8*)pg1;
    bf16x8 vu0 = *(const bf16x8*)pu0;
    bf16x8 vu1 = *(const bf16x8*)pu1;
    g00 = MFMA(va0, vg0, g00);
    g01 = MFMA(va0, vg1, g01);
    g10 = MFMA(va1, vg0, g10);
    g11 = MFMA(va1, vg1, g11);
    u00 = MFMA(va0, vu0, u00);
    u01 = MFMA(va0, vu1, u01);
    u10 = MFMA(va1, vu0, u10);
    u11 = MFMA(va1, vu1, u11);
    pa0 += 32; pa1 += 32; pg0 += 32; pg1 += 32; pu0 += 32; pu1 += 32;
  }
  int crow = (lane >> 4) * 4, ccol = lane & 15;
  f32x4 gg[2][2] = {{g00, g01}, {g10, g11}};
  f32x4 uu[2][2] = {{u00, u01}, {u10, u11}};
  #pragma unroll
  for (int mi = 0; mi < 2; ++mi)
  #pragma unroll
  for (int ni = 0; ni < 2; ++ni)
  #pragma unroll
  for (int r = 0; r < 4; ++r) {
    int row = m0 + mi * 16 + crow + r;
    int col = n0 + ni * 16 + ccol;
    float g = gg[mi][ni][r], u = uu[mi][ni][r];
    H[(size_t)row * ldc + col] = f2b(silu(g) * u);
  }
}

// ---------------- causal depthwise conv (4 taps) + silu; hi/lo in -> hi/lo out ----------------
__global__ __launch_bounds__(256) void k_conv(const bf16* __restrict__ xh, const bf16* __restrict__ xl,
                                              const float* __restrict__ cw, const float* __restrict__ cb,
                                              bf16* __restrict__ oh, bf16* __restrict__ ol){
  int d = blockIdx.x * 256 + threadIdx.x;   // [0,2048)
  int row = blockIdx.y;                     // [0,8192)
  int s = row & (Sz - 1);
  size_t base = (size_t)row * DIz + d;
  float w0 = cw[d*4+0], w1 = cw[d*4+1], w2 = cw[d*4+2], w3 = cw[d*4+3];
  float x0 = (s >= 3) ? rc(xh, xl, base - 3*DIz) : 0.f;
  float x1 = (s >= 2) ? rc(xh, xl, base - 2*DIz) : 0.f;
  float x2 = (s >= 1) ? rc(xh, xl, base - 1*DIz) : 0.f;
  float x3 = rc(xh, xl, base);
  float v = cb[d] + w0*x0 + w1*x1 + w2*x2 + w3*x3;
  float o = v / (1.f + expf(-v));
  split2(o, oh[base], ol[base]);
}

// ---------------- chunked selective scan, per d-half (fp32 via hi/lo reconstruct) ----------------
// dt/y: [8192, NDH] ld NDH. xi/res pointers pre-offset by d0, ld DIz. A_log pre-offset by d0*16.
__global__ __launch_bounds__(256) void k_scan1(const bf16* __restrict__ dth, const bf16* __restrict__ dtl,
                                               const bf16* __restrict__ xih, const bf16* __restrict__ xil,
                                               const bf16* __restrict__ xdh, const bf16* __restrict__ xdl,
                                               const float* __restrict__ A_log,
                                               float* __restrict__ P, float* __restrict__ R){
  int b = blockIdx.y, c = blockIdx.z;
  int d = blockIdx.x * 16 + (threadIdx.x >> 4);   // [0, NDH)
  int n = threadIdx.x & 15;
  float Adn = -expf(A_log[d * DSz + n]);
  float h = 0.f, p = 1.f;
  int s0 = c * CLEN;
  #pragma unroll 2
  for (int s = s0; s < s0 + CLEN; ++s) {
    size_t row = (size_t)b * Sz + s;
    float dtv = rc(dth, dtl, row * NDH + d);
    float xiv = rc(xih, xil, row * DIz + d);
    float Bn  = rc(xdh, xdl, row * 128 + 64 + n);
    float da = expf(dtv * Adn);
    h = da * h + dtv * Bn * xiv;
    p *= da;
  }
  size_t idx = (((size_t)c * Bz + b) * NDH + d) * DSz + n;
  P[idx] = p; R[idx] = h;
}
__global__ __launch_bounds__(256) void k_scan2(const float* __restrict__ P, const float* __restrict__ R,
                                               float* __restrict__ Hin){
  int i = blockIdx.x * 256 + threadIdx.x;   // [0, Bz*NDH*DSz)
  float h = 0.f;
  #pragma unroll
  for (int c = 0; c < NCHUNK; ++c) {
    size_t idx = (size_t)c * (Bz * NDH * DSz) + i;
    Hin[idx] = h;
    h = P[idx] * h + R[idx];
  }
}
__global__ __launch_bounds__(256) void k_scan3(const bf16* __restrict__ dth, const bf16* __restrict__ dtl,
                                               const bf16* __restrict__ xih, const bf16* __restrict__ xil,
                                               const bf16* __restrict__ xdh, const bf16* __restrict__ xdl,
                                               const bf16* __restrict__ resh, const bf16* __restrict__ resl,
                                               const float* __restrict__ A_log, const float* __restrict__ Dsk,
                                               const float* __restrict__ Hin,
                                               bf16* __restrict__ yh, bf16* __restrict__ yl){
  int b = blockIdx.y, c = blockIdx.z;
  int d = blockIdx.x * 16 + (threadIdx.x >> 4);
  int n = threadIdx.x & 15;
  float Adn = -expf(A_log[d * DSz + n]);
  float Dv = Dsk[d];
  size_t sidx = (((size_t)c * Bz + b) * NDH + d) * DSz + n;
  float h = Hin[sidx];
  int s0 = c * CLEN;
  for (int s = s0; s < s0 + CLEN; ++s) {
    size_t row = (size_t)b * Sz + s;
    float dtv = rc(dth, dtl, row * NDH + d);
    float xiv = rc(xih, xil, row * DIz + d);
    float Bn  = rc(xdh, xdl, row * 128 + 64 + n);
    float Cn  = rc(xdh, xdl, row * 128 + 80 + n);
    float da = expf(dtv * Adn);
    h = da * h + dtv * Bn * xiv;
    float p = h * Cn;
    p += __shfl_xor(p, 1); p += __shfl_xor(p, 2); p += __shfl_xor(p, 4); p += __shfl_xor(p, 8);
    if (n == 0) {
      float resv = rc(resh, resl, row * DIz + d);
      float yv = (p + xiv * Dv) * (resv / (1.f + expf(-resv)));
      split2(yv, yh[row * NDH + d], yl[row * NDH + d]);
    }
  }
}

// ---------------- MoE gate: inline fp32 rmsnorm + scores + softmax + top-2 ----------------
__global__ __launch_bounds__(64) void k_gate(const float* __restrict__ m, const float* __restrict__ nw,
                                             const float* __restrict__ gw, const float* __restrict__ gb,
                                             int* __restrict__ topi, float* __restrict__ topw,
                                             int* __restrict__ counts){
  int t = blockIdx.x;
  int lane = threadIdx.x;
  const float* xr = m + (size_t)t * Dz;
  float xv[16];
  float ss = 0.f;
  #pragma unroll
  for (int j = 0; j < 16; ++j) { xv[j] = xr[lane + j * 64]; ss += xv[j] * xv[j]; }
  #pragma unroll
  for (int o = 32; o; o >>= 1) ss += __shfl_xor(ss, o);
  float sc = rsqrtf(ss * (1.f / Dz) + 1e-6f);
  #pragma unroll
  for (int j = 0; j < 16; ++j) xv[j] *= sc * nw[lane + j * 64];
  float acc[8] = {0.f,0.f,0.f,0.f,0.f,0.f,0.f,0.f};
  #pragma unroll
  for (int j = 0; j < 16; ++j) {
    #pragma unroll
    for (int e = 0; e < 8; ++e) acc[e] += xv[j] * gw[e * Dz + lane + j * 64];
  }
  #pragma unroll
  for (int e = 0; e < 8; ++e) {
    float v = acc[e];
    #pragma unroll
    for (int o = 32; o; o >>= 1) v += __shfl_xor(v, o);
    acc[e] = v;
  }
  if (lane == 0) {
    float mx = acc[0];
    #pragma unroll
    for (int e = 1; e < 8; ++e) mx = fmaxf(mx, acc[e]);
    float scr[8]; float sum = 0.f;
    #pragma unroll
    for (int e = 0; e < 8; ++e) { scr[e] = expf(acc[e] - mx); sum += scr[e]; }
    float inv = 1.f / sum;
    #pragma unroll
    for (int e = 0; e < 8; ++e) scr[e] *= inv;
    int i0 = 0; float b0 = -1e30f;
    #pragma unroll
    for (int e = 0; e < 8; ++e) { float kv = scr[e] + gb[e]; if (kv > b0) { b0 = kv; i0 = e; } }
    int i1 = -1; float b1 = -1e30f;
    #pragma unroll
    for (int e = 0; e < 8; ++e) { if (e == i0) continue; float kv = scr[e] + gb[e]; if (kv > b1) { b1 = kv; i1 = e; } }
    float w0 = scr[i0], w1 = scr[i1];
    float wn = 1.f / (w0 + w1 + 1e-9f);
    topi[t*2] = i0; topi[t*2+1] = i1;
    topw[t*2] = w0 * wn; topw[t*2+1] = w1 * wn;
    atomicAdd(&counts[i0], 1); atomicAdd(&counts[i1], 1);
  }
}

__global__ void k_offs(const int* __restrict__ counts, int* __restrict__ offs, int* __restrict__ fill){
  if (threadIdx.x == 0) {
    int o = 0;
    for (int e = 0; e < 8; ++e) { offs[e] = o; o += ((counts[e] + 63) & ~63); }
    offs[8] = o;
  }
  if (threadIdx.x < 8) fill[threadIdx.x] = 0;
}

__global__ __launch_bounds__(256) void k_scatter(const int* __restrict__ topi, const float* __restrict__ topw,
                                                 const int* __restrict__ offs, int* __restrict__ fill,
                                                 int* __restrict__ toks, float* __restrict__ wslot,
                                                 int* __restrict__ slot_of){
  int i = blockIdx.x * 256 + threadIdx.x;
  if (i >= Tz * 2) return;
  int e = topi[i];
  int pos = atomicAdd(&fill[e], 1);
  int slot = offs[e] + pos;
  toks[slot] = i >> 1;
  wslot[slot] = topw[i];
  slot_of[i] = slot;
}

// ---------------- final combine: out = m + w0*down0 + w1*down1 ----------------
__global__ __launch_bounds__(256) void k_combine(const float* __restrict__ m,
                                                 const bf16* __restrict__ Hd, const int* __restrict__ slot_of,
                                                 float* __restrict__ out){
  int t = blockIdx.x;
  int ci = threadIdx.x * 4;
  int s0 = slot_of[t*2], s1 = slot_of[t*2+1];
  size_t base = (size_t)t * Dz + ci;
  float4 mv = *(const float4*)(m + base);
  ushort4 h0 = *(const ushort4*)((const unsigned short*)Hd + (size_t)s0 * Dz + ci);
  ushort4 h1 = *(const ushort4*)((const unsigned short*)Hd + (size_t)s1 * Dz + ci);
  out[base+0] = mv.x + us2f(h0.x) + us2f(h1.x);
  out[base+1] = mv.y + us2f(h0.y) + us2f(h1.y);
  out[base+2] = mv.z + us2f(h0.z) + us2f(h1.z);
  out[base+3] = mv.w + us2f(h0.w) + us2f(h1.w);
}

extern "C" void kernel_launch(void* const* d_in, const int* in_sizes, int n_in,
                              void* d_out, int out_size, void* d_ws, size_t ws_size,
                              hipStream_t stream) {
  (void)in_sizes; (void)n_in; (void)out_size;
  const float* x         = (const float*)d_in[0];
  const float* norm_w    = (const float*)d_in[1];
  const float* in_proj   = (const float*)d_in[2];
  const float* conv_w    = (const float*)d_in[3];
  const float* conv_b    = (const float*)d_in[4];
  const float* x_proj    = (const float*)d_in[5];
  const float* dt_proj   = (const float*)d_in[6];
  const float* dt_proj_b = (const float*)d_in[7];
  const float* A_log     = (const float*)d_in[8];
  const float* D_skip    = (const float*)d_in[9];
  const float* out_proj  = (const float*)d_in[10];
  const float* gate_w    = (const float*)d_in[11];
  const float* gate_b    = (const float*)d_in[12];
  const float* w_gate    = (const float*)d_in[13];
  const float* w_up      = (const float*)d_in[14];
  const float* w_down    = (const float*)d_in[15];
  const float* ws_gate   = (const float*)d_in[16];
  const float* ws_up     = (const float*)d_in[17];
  const float* ws_down   = (const float*)d_in[18];
  float* out = (float*)d_out;

  const size_t MB = 1024 * 1024;
  const size_t NEED = 251 * MB;
  if (ws_size < NEED) {
    k_fill<<<dim3(1), dim3(256), 0, stream>>>(out, (float)(ws_size / MB));
    fprintf(stderr, "kernel_launch: ws_size=%zu < needed=%zu\n", ws_size, NEED);
    return;
  }
  char* P = (char*)d_ws;
  // ---- phase A (mamba, split precision, two d-halves for scan) ----
  bf16* res_h = (bf16*)(P + 0*MB);     // [8192,2048] 32MB   in_proj -> scan3(h1)
  bf16* res_l = (bf16*)(P + 32*MB);
  bf16* xi_h  = (bf16*)(P + 64*MB);    // [8192,2048] 32MB   conv -> scan3(h1)
  bf16* xi_l  = (bf16*)(P + 96*MB);
  bf16* xd_h  = (bf16*)(P + 128*MB);   // [8192,128]   2MB   x_proj -> scan (both halves)
  bf16* xd_l  = (bf16*)(P + 130*MB);
  bf16* dth   = (bf16*)(P + 132*MB);   // [8192,1024] 16MB   per-half dt
  bf16* dtl   = (bf16*)(P + 148*MB);
  float* scanP = (float*)(P + 164*MB); // [16,2,1024,16] 2MB each
  float* scanR = (float*)(P + 166*MB);
  float* scanH = (float*)(P + 168*MB);
  bf16* y_h   = (bf16*)(P + 176*MB);   // [8192,1024] 16MB   per-half y
  bf16* y_l   = (bf16*)(P + 192*MB);
  float* mbuf = (float*)(P + 208*MB);  // [8192,1024] f32 32MB  (persists into phase B)
  // prologue staging (dead before the scan loop):
  bf16* nrm_h = (bf16*)(P + 128*MB);   // 16MB, dead after in_proj (xd overlays later)
  bf16* nrm_l = (bf16*)(P + 144*MB);
  bf16* iph   = (bf16*)(P + 160*MB);   // 8MB each, dead after in_proj
  bf16* ipl   = (bf16*)(P + 168*MB);
  bf16* xzi_h = (bf16*)(P + 176*MB);   // [8192,2048] 32MB each, dead after conv
  bf16* xzi_l = (bf16*)(P + 208*MB);
  // persistent small weights (240..250)
  bf16* xph   = (bf16*)(P + 240*MB);             // [128,2048] 0.5MB each
  bf16* xpl   = (bf16*)(P + 240*MB + 512*1024);
  bf16* dph   = (bf16*)(P + 241*MB);             // [2048,64] 0.25MB each
  bf16* dpl   = (bf16*)(P + 241*MB + 256*1024);
  bf16* oph   = (bf16*)(P + 242*MB);             // [1024,2048] 4MB each
  bf16* opl   = (bf16*)(P + 246*MB);
  // ---- phase B (MoE) overlay — all source regions dead by write time ----
  bf16* n2b   = (bf16*)(P + 0*MB);     // 16MB  over res_h
  bf16* wgh   = (bf16*)(P + 16*MB);    // 16MB  over res_l
  bf16* wuh   = (bf16*)(P + 32*MB);
  bf16* wdh   = (bf16*)(P + 48*MB);
  bf16* wsg   = (bf16*)(P + 64*MB);    // 4MB
  bf16* wsu   = (bf16*)(P + 68*MB);
  bf16* wsd   = (bf16*)(P + 72*MB);
  bf16* Hbuf  = (bf16*)(P + 76*MB);    // [SLOTCAP,1024] 33MB
  bf16* Hd    = (bf16*)(P + 109*MB);   // 33MB
  bf16* Sh    = (bf16*)(P + 142*MB);   // [8192,2048] 32MB (142..174)
  char* Rt    = P + 250*MB;            // routing (persistent region)
  int*   counts  = (int*)(Rt);
  int*   offsb   = (int*)(Rt + 64);
  int*   fill    = (int*)(Rt + 128);
  int*   topi    = (int*)(Rt + 1024);
  float* topw    = (float*)(Rt + 1024 + 65536);
  int*   toks    = (int*)(Rt + 1024 + 2*65536);
  float* wslot   = (float*)(Rt + 1024 + 2*65536 + 67584);
  int*   slot_of = (int*)(Rt + 1024 + 2*65536 + 2*67584);

  auto spw = [&](const float* s, bf16* dh, bf16* dl, size_t n){
    k_split<<<dim3((unsigned)((n/4 + 255)/256)), dim3(256), 0, stream>>>(s, dh, dl, (int)n);
  };
  auto cvt = [&](const float* s, bf16* d, size_t n){
    k_f2bf<<<dim3((unsigned)((n/4 + 255)/256)), dim3(256), 0, stream>>>(s, d, (int)n);
  };

  // mamba weight splits
  spw(in_proj,  iph, ipl, (size_t)4096*1024);
  spw(dt_proj,  dph, dpl, (size_t)2048*64);
  spw(out_proj, oph, opl, (size_t)1024*2048);
  k_split_pad<<<dim3(256), dim3(256), 0, stream>>>(x_proj, xph, xpl);

  // 1. rmsnorm(x) -> normed hi/lo
  k_rmsnorm<true><<<dim3(Tz), dim3(256), 0, stream>>>(x, norm_w, nrm_h, nrm_l);
  // 2. in_proj (split): dual store -> xzi (cols 0..2047), res (cols 2048..4095)
  k_gemm_sp<1><<<dim3(Tz/64, 4096/64), dim3(256), 0, stream>>>(
      nrm_h, nrm_l, Dz, iph, ipl, Dz, xzi_h, xzi_l, res_h, res_l, nullptr, 0, Dz, nullptr);
  // 3. causal conv + silu -> xi hi/lo   (nrm/ipW dead)
  k_conv<<<dim3(DIz/256, Tz), dim3(256), 0, stream>>>(xzi_h, xzi_l, conv_w, conv_b, xi_h, xi_l);
  // 4. x_proj (split) -> xdbl hi/lo (N padded to 128)  (xzi dead; xd overlays nrm)
  k_gemm_sp<0><<<dim3(Tz/64, 128/64), dim3(256), 0, stream>>>(
      xi_h, xi_l, DIz, xph, xpl, DIz, xd_h, xd_l, nullptr, nullptr, nullptr, 128, DIz, nullptr);

  // 5-7. per d-half: dt_proj -> scan -> out_proj partial
  for (int h = 0; h < 2; ++h) {
    int d0 = h * NDH;
    // dt_proj(half) + softplus -> dt hi/lo [8192,1024]
    k_gemm_sp<2><<<dim3(Tz/64, NDH/64), dim3(256), 0, stream>>>(
        xd_h, xd_l, 128, dph + (size_t)d0*DTRz, dpl + (size_t)d0*DTRz, DTRz,
        dth, dtl, nullptr, nullptr, nullptr, NDH, DTRz, dt_proj_b + d0);
    // chunked scan on this half
    k_scan1<<<dim3(NDH/16, Bz, NCHUNK), dim3(256), 0, stream>>>(
        dth, dtl, xi_h + d0, xi_l + d0, xd_h, xd_l, A_log + (size_t)d0*DSz, scanP, scanR);
    k_scan2<<<dim3(Bz*NDH*DSz/256), dim3(256), 0, stream>>>(scanP, scanR, scanH);
    k_scan3<<<dim3(NDH/16, Bz, NCHUNK), dim3(256), 0, stream>>>(
        dth, dtl, xi_h + d0, xi_l + d0, xd_h, xd_l, res_h + d0, res_l + d0,
        A_log + (size_t)d0*DSz, D_skip + d0, scanH, y_h, y_l);
    // out_proj partial: h0: mbuf = v + x ; h1: mbuf += v
    if (h == 0)
      k_gemm_sp<3><<<dim3(Tz/64, Dz/64), dim3(256), 0, stream>>>(
          y_h, y_l, NDH, oph + d0, opl + d0, DIz, nullptr, nullptr, nullptr, nullptr,
          mbuf, Dz, NDH, x);
    else
      k_gemm_sp<4><<<dim3(Tz/64, Dz/64), dim3(256), 0, stream>>>(
          y_h, y_l, NDH, oph + d0, opl + d0, DIz, nullptr, nullptr, nullptr, nullptr,
          mbuf, Dz, NDH, nullptr);
  }

  // MoE weight conversion (plain bf16; res/xi/dt/scan regions dead)
  cvt(w_gate,   wgh, (size_t)8*1024*1024);
  cvt(w_up,     wuh, (size_t)8*1024*1024);
  cvt(w_down,   wdh, (size_t)8*1024*1024);
  cvt(ws_gate,  wsg, (size_t)2048*1024);
  cvt(ws_up,    wsu, (size_t)2048*1024);
  cvt(ws_down,  wsd, (size_t)1024*2048);
  // 8. rmsnorm(m) -> n2 bf16
  k_rmsnorm<false><<<dim3(Tz), dim3(256), 0, stream>>>(mbuf, norm_w, n2b, nullptr);
  // 9. gate (inline fp32 norm) + routing
  k_zero_counts<<<dim3(1), dim3(64), 0, stream>>>(counts);
  k_gate<<<dim3(Tz), dim3(64), 0, stream>>>(mbuf, norm_w, gate_w, gate_b, topi, topw, counts);
  k_offs<<<dim3(1), dim3(64), 0, stream>>>(counts, offsb, fill);
  k_scatter<<<dim3(Tz*2/256), dim3(256), 0, stream>>>(topi, topw, offsb, fill, toks, wslot, slot_of);
  // 10. routed experts: GLU then down (scaled by gate weight)
  k_glu<true><<<dim3(SLOTCAP/64, Fz/64), dim3(256), 0, stream>>>(
      n2b, Dz, wgh, wuh, Dz, (size_t)Fz*Dz, Hbuf, Fz, Dz, offsb, toks, counts);
  k_gemm_bt<4,true><<<dim3(SLOTCAP/64, Dz/64), dim3(256), 0, stream>>>(
      Hbuf, Fz, wdh, Fz, (size_t)Dz*Fz, Hd, Dz, Fz, wslot, offsb);
  // 11. shared expert GLU -> Sh
  k_glu<false><<<dim3(Tz/64, FSz/64), dim3(256), 0, stream>>>(
      n2b, Dz, wsg, wsu, Dz, 0, Sh, FSz, Dz, nullptr, nullptr, nullptr);
  // 12. combine -> out = m + routed
  k_combine<<<dim3(Tz), dim3(256), 0, stream>>>(mbuf, Hd, slot_of, out);
  // 13. shared down: out += Sh @ ws_down^T
  k_gemm_bt<5,false><<<dim3(Tz/64, Dz/64), dim3(256), 0, stream>>>(
      Sh, FSz, wsd, FSz, 0, out, Dz, FSz, nullptr, nullptr);
}

// Round 5
// 2264.545 us; speedup vs baseline: 1.7845x; 1.7845x over previous
//
#include <hip/hip_runtime.h>
#include <hip/hip_bf16.h>
#include <cstdio>

#define Bz 2
#define Sz 4096
#define Dz 1024
#define DIz 2048
#define DSz 16
#define DTRz 64
#define NE 8
#define Fz 1024
#define FSz 2048
#define Tz (Bz*Sz)            // 8192 tokens
#define NCHUNK 16
#define CLEN (Sz/NCHUNK)      // 256
#define NDH 1024              // d-half width
#define SLOTCAP 17408         // 136 tiles * 128

typedef __hip_bfloat16 bf16;
typedef short bf16x8 __attribute__((ext_vector_type(8)));
typedef float f32x4 __attribute__((ext_vector_type(4)));

#define MFMA(a,b,c) __builtin_amdgcn_mfma_f32_16x16x32_bf16(a,b,c,0,0,0)

__device__ __forceinline__ float b2f(bf16 v){ return __bfloat162float(v); }
__device__ __forceinline__ bf16  f2b(float v){ return __float2bfloat16(v); }
__device__ __forceinline__ float us2f(unsigned short u){
  union { unsigned int i; float f; } v; v.i = ((unsigned int)u) << 16; return v.f;
}
__device__ __forceinline__ float silu(float v){ return v / (1.f + __expf(-v)); }
__device__ __forceinline__ void split2(float v, bf16& h, bf16& l){ h = f2b(v); l = f2b(v - b2f(h)); }
__device__ __forceinline__ float rc(const bf16* __restrict__ h, const bf16* __restrict__ l, size_t i){
  return b2f(h[i]) + b2f(l[i]);
}
// async global -> LDS, 16B per lane; lds base wave-uniform, HW adds lane*16
__device__ __forceinline__ void gload16(const bf16* g, bf16* l){
  __builtin_amdgcn_global_load_lds(
      (const __attribute__((address_space(1))) void*)g,
      (__attribute__((address_space(3))) void*)l, 16, 0, 0);
}

// ---------------- guard diagnostic ----------------
__global__ void k_fill(float* __restrict__ o, float v){ o[threadIdx.x] = v; }

// ---------------- weight conversion ----------------
__global__ __launch_bounds__(256) void k_f2bf(const float* __restrict__ s, bf16* __restrict__ d, int n){
  int i = (blockIdx.x * 256 + threadIdx.x) * 4;
  if (i + 3 < n) {
    float4 v = *(const float4*)(s + i);
    d[i] = f2b(v.x); d[i+1] = f2b(v.y); d[i+2] = f2b(v.z); d[i+3] = f2b(v.w);
  }
}
__global__ __launch_bounds__(256) void k_split(const float* __restrict__ s, bf16* __restrict__ dh,
                                               bf16* __restrict__ dl, int n){
  int i = (blockIdx.x * 256 + threadIdx.x) * 4;
  if (i + 3 < n) {
    float4 v = *(const float4*)(s + i);
    split2(v.x, dh[i],   dl[i]);
    split2(v.y, dh[i+1], dl[i+1]);
    split2(v.z, dh[i+2], dl[i+2]);
    split2(v.w, dh[i+3], dl[i+3]);
  }
}
// x_proj [96,2048] -> padded [128,2048] hi/lo (pad rows = 0)
__global__ __launch_bounds__(256) void k_split_pad(const float* __restrict__ s, bf16* __restrict__ dh,
                                                   bf16* __restrict__ dl){
  int i = (blockIdx.x * 256 + threadIdx.x) * 4;
  int row = i >> 11;
  if (row < 96) {
    float4 v = *(const float4*)(s + i);
    split2(v.x, dh[i],   dl[i]);
    split2(v.y, dh[i+1], dl[i+1]);
    split2(v.z, dh[i+2], dl[i+2]);
    split2(v.w, dh[i+3], dl[i+3]);
  } else {
    bf16 z = f2b(0.f);
    dh[i]=z; dh[i+1]=z; dh[i+2]=z; dh[i+3]=z;
    dl[i]=z; dl[i+1]=z; dl[i+2]=z; dl[i+3]=z;
  }
}

__global__ void k_zero_counts(int* __restrict__ c){
  if (threadIdx.x < NE) c[threadIdx.x] = 0;
}

// ---------------- rmsnorm (f32 in). HL: hi/lo out; else single bf16 out ----------------
template<bool HL>
__global__ __launch_bounds__(256) void k_rmsnorm(const float* __restrict__ x, const float* __restrict__ w,
                                                 bf16* __restrict__ oh, bf16* __restrict__ ol){
  int row = blockIdx.x;
  const float* xr = x + (size_t)row * Dz;
  int c4 = threadIdx.x * 4;
  float4 v = *(const float4*)(xr + c4);
  float ss = v.x*v.x + v.y*v.y + v.z*v.z + v.w*v.w;
  #pragma unroll
  for (int o = 32; o; o >>= 1) ss += __shfl_xor(ss, o);
  __shared__ float sred[4];
  if ((threadIdx.x & 63) == 0) sred[threadIdx.x >> 6] = ss;
  __syncthreads();
  float tot = sred[0] + sred[1] + sred[2] + sred[3];
  float sc = rsqrtf(tot * (1.f / Dz) + 1e-6f);
  float4 wv = *(const float4*)(w + c4);
  float o0 = v.x*sc*wv.x, o1 = v.y*sc*wv.y, o2 = v.z*sc*wv.z, o3 = v.w*sc*wv.w;
  size_t ci = (size_t)row * Dz + c4;
  if (HL) {
    split2(o0, oh[ci], ol[ci]);   split2(o1, oh[ci+1], ol[ci+1]);
    split2(o2, oh[ci+2], ol[ci+2]); split2(o3, oh[ci+3], ol[ci+3]);
  } else {
    oh[ci] = f2b(o0); oh[ci+1] = f2b(o1); oh[ci+2] = f2b(o2); oh[ci+3] = f2b(o3);
  }
}

// ======== naive 64x64 split GEMM (kept for small shapes: x_proj EPI=0, dt_proj EPI=2) ========
template<int EPI>
__global__ __launch_bounds__(256) void k_gemm_sp(
    const bf16* __restrict__ Ah, const bf16* __restrict__ Al, int lda,
    const bf16* __restrict__ Bh, const bf16* __restrict__ Bl, int ldb,
    bf16* __restrict__ C1h, bf16* __restrict__ C1l,
    float* __restrict__ Cf, int ldc, int K,
    const float* __restrict__ epi)
{
  int row0 = blockIdx.x * 64;
  int lane = threadIdx.x & 63, wid = threadIdx.x >> 6;
  int m0 = row0 + (wid >> 1) * 32;
  int n0 = blockIdx.y * 64 + (wid & 1) * 32;
  int lr = lane & 15, lk = (lane >> 4) * 8;
  const bf16 *pah0 = Ah + (size_t)(m0+lr)*lda + lk, *pah1 = pah0 + (size_t)16*lda;
  const bf16 *pal0 = Al + (size_t)(m0+lr)*lda + lk, *pal1 = pal0 + (size_t)16*lda;
  const bf16 *pbh0 = Bh + (size_t)(n0+lr)*ldb + lk, *pbh1 = pbh0 + (size_t)16*ldb;
  const bf16 *pbl0 = Bl + (size_t)(n0+lr)*ldb + lk, *pbl1 = pbl0 + (size_t)16*ldb;
  f32x4 a00 = {0.f,0.f,0.f,0.f}, a01 = a00, a10 = a00, a11 = a00;
  for (int k = 0; k < K; k += 32) {
    bf16x8 AH0 = *(const bf16x8*)pah0, AH1 = *(const bf16x8*)pah1;
    bf16x8 AL0 = *(const bf16x8*)pal0, AL1 = *(const bf16x8*)pal1;
    bf16x8 BH0 = *(const bf16x8*)pbh0, BH1 = *(const bf16x8*)pbh1;
    bf16x8 BL0 = *(const bf16x8*)pbl0, BL1 = *(const bf16x8*)pbl1;
    a00 = MFMA(AH0, BH0, a00); a00 = MFMA(AH0, BL0, a00); a00 = MFMA(AL0, BH0, a00);
    a01 = MFMA(AH0, BH1, a01); a01 = MFMA(AH0, BL1, a01); a01 = MFMA(AL0, BH1, a01);
    a10 = MFMA(AH1, BH0, a10); a10 = MFMA(AH1, BL0, a10); a10 = MFMA(AL1, BH0, a10);
    a11 = MFMA(AH1, BH1, a11); a11 = MFMA(AH1, BL1, a11); a11 = MFMA(AL1, BH1, a11);
    pah0 += 32; pah1 += 32; pal0 += 32; pal1 += 32;
    pbh0 += 32; pbh1 += 32; pbl0 += 32; pbl1 += 32;
  }
  int crow = (lane >> 4) * 4, ccol = lane & 15;
  f32x4 accs[2][2] = {{a00, a01}, {a10, a11}};
  #pragma unroll
  for (int mi = 0; mi < 2; ++mi)
  #pragma unroll
  for (int ni = 0; ni < 2; ++ni)
  #pragma unroll
  for (int r = 0; r < 4; ++r) {
    int row = m0 + mi * 16 + crow + r;
    int col = n0 + ni * 16 + ccol;
    float v = accs[mi][ni][r];
    size_t ci = (size_t)row * ldc + col;
    if (EPI == 0) split2(v, C1h[ci], C1l[ci]);
    else if (EPI == 2) {
      float t = v + epi[col];
      float sp = (t > 20.f) ? t : log1pf(expf(t));
      split2(sp, C1h[ci], C1l[ci]);
    }
  }
}

// ======== 128x128 LDS-staged split GEMM (3-term). EPI: 1=in_proj dual store,
//          3 = Cf = v + epi[ci], 4 = Cf += v ========
template<int EPI>
__global__ __launch_bounds__(256) void k_gemm_sp128(
    const bf16* __restrict__ Ah, const bf16* __restrict__ Al, int lda,
    const bf16* __restrict__ Bh, const bf16* __restrict__ Bl, int ldb,
    bf16* __restrict__ C1h, bf16* __restrict__ C1l,
    bf16* __restrict__ C2h, bf16* __restrict__ C2l,
    float* __restrict__ Cf, int ldc, int K,
    const float* __restrict__ epi)
{
  __shared__ __align__(16) bf16 sAh[4096], sAl[4096], sBh[4096], sBl[4096];
  int tid = threadIdx.x;
  int lane = tid & 63, w = tid >> 6;
  int row0 = blockIdx.x * 128, n00 = blockIdx.y * 128;
  int wr = (w >> 1) * 64, wc = (w & 1) * 64;
  int srow = w * 32 + (lane >> 2);
  int scol = (lane & 3) * 8;
  const bf16* pAh = Ah + (size_t)(row0 + srow) * lda + scol;
  const bf16* pAl = Al + (size_t)(row0 + srow) * lda + scol;
  const bf16* pBh = Bh + (size_t)(n00 + srow) * ldb + scol;
  const bf16* pBl = Bl + (size_t)(n00 + srow) * ldb + scol;
  int lr = lane & 15, lk = (lane >> 4) * 8;
  f32x4 acc[4][4];
  #pragma unroll
  for (int i = 0; i < 4; ++i)
    #pragma unroll
    for (int j = 0; j < 4; ++j) acc[i][j] = {0.f,0.f,0.f,0.f};
  for (int kt = 0; kt < K; kt += 32) {
    if (kt) __syncthreads();
    #pragma unroll
    for (int j = 0; j < 2; ++j) {
      int lb = (w * 128 + j * 64) * 8;
      size_t goa = (size_t)j * 16 * lda + kt;
      size_t gob = (size_t)j * 16 * ldb + kt;
      gload16(pAh + goa, &sAh[lb]);
      gload16(pAl + goa, &sAl[lb]);
      gload16(pBh + gob, &sBh[lb]);
      gload16(pBl + gob, &sBl[lb]);
    }
    __syncthreads();
    bf16x8 fa[4], fb[4], ft[4];
    #pragma unroll
    for (int i = 0; i < 4; ++i) {
      fa[i] = *(const bf16x8*)&sAh[(wr + i*16 + lr) * 32 + lk];
      fb[i] = *(const bf16x8*)&sBh[(wc + i*16 + lr) * 32 + lk];
    }
    #pragma unroll
    for (int mi = 0; mi < 4; ++mi)
      #pragma unroll
      for (int ni = 0; ni < 4; ++ni)
        acc[mi][ni] = MFMA(fa[mi], fb[ni], acc[mi][ni]);
    #pragma unroll
    for (int i = 0; i < 4; ++i) ft[i] = *(const bf16x8*)&sBl[(wc + i*16 + lr) * 32 + lk];
    #pragma unroll
    for (int mi = 0; mi < 4; ++mi)
      #pragma unroll
      for (int ni = 0; ni < 4; ++ni)
        acc[mi][ni] = MFMA(fa[mi], ft[ni], acc[mi][ni]);
    #pragma unroll
    for (int i = 0; i < 4; ++i) ft[i] = *(const bf16x8*)&sAl[(wr + i*16 + lr) * 32 + lk];
    #pragma unroll
    for (int mi = 0; mi < 4; ++mi)
      #pragma unroll
      for (int ni = 0; ni < 4; ++ni)
        acc[mi][ni] = MFMA(ft[mi], fb[ni], acc[mi][ni]);
  }
  int crow = (lane >> 4) * 4, ccol = lane & 15;
  #pragma unroll
  for (int mi = 0; mi < 4; ++mi)
  #pragma unroll
  for (int ni = 0; ni < 4; ++ni)
  #pragma unroll
  for (int r = 0; r < 4; ++r) {
    int row = row0 + wr + mi * 16 + crow + r;
    int col = n00 + wc + ni * 16 + ccol;
    float v = acc[mi][ni][r];
    if (EPI == 1) {
      size_t ci = (size_t)row * 2048 + (col & 2047);
      bf16 hv, lv; split2(v, hv, lv);
      if (col < 2048) { C1h[ci] = hv; C1l[ci] = lv; }
      else            { C2h[ci] = hv; C2l[ci] = lv; }
    } else if (EPI == 3) {
      size_t ci = (size_t)row * ldc + col;
      Cf[ci] = v + epi[ci];
    } else if (EPI == 4) {
      size_t ci = (size_t)row * ldc + col;
      Cf[ci] += v;
    }
  }
}

// ======== 128x128 LDS-staged plain GEMM. EPI: 4 = v*wslot[row] (guarded) -> bf16,
//          5 = f32 accumulate ========
template<int EPI, bool ROUTED>
__global__ __launch_bounds__(256) void k_gemm128(
    const bf16* __restrict__ A, int lda,
    const bf16* __restrict__ Bw, int ldb, size_t estride,
    void* __restrict__ Cp, int ldc, int K,
    const float* __restrict__ epi,
    const int* __restrict__ offs, const int* __restrict__ counts)
{
  __shared__ __align__(16) bf16 sA[4096], sB[4096];
  int row0 = 0, e = 0;
  if (ROUTED) {
    int bid = blockIdx.x, cum = 0; e = -1;
    #pragma unroll
    for (int i = 0; i < 8; ++i) {
      int tiles = (offs[i+1] - offs[i]) >> 7;
      if (e < 0 && bid < cum + tiles) { e = i; row0 = offs[i] + ((bid - cum) << 7); }
      cum += tiles;
    }
    if (e < 0) return;
  } else {
    row0 = blockIdx.x * 128;
  }
  const bf16* Bm = Bw + (size_t)e * estride;
  int tid = threadIdx.x;
  int lane = tid & 63, w = tid >> 6;
  int n00 = blockIdx.y * 128;
  int wr = (w >> 1) * 64, wc = (w & 1) * 64;
  int srow = w * 32 + (lane >> 2);
  int scol = (lane & 3) * 8;
  const bf16* pA = A + (size_t)(row0 + srow) * lda + scol;
  const bf16* pB = Bm + (size_t)(n00 + srow) * ldb + scol;
  int lr = lane & 15, lk = (lane >> 4) * 8;
  f32x4 acc[4][4];
  #pragma unroll
  for (int i = 0; i < 4; ++i)
    #pragma unroll
    for (int j = 0; j < 4; ++j) acc[i][j] = {0.f,0.f,0.f,0.f};
  for (int kt = 0; kt < K; kt += 32) {
    if (kt) __syncthreads();
    #pragma unroll
    for (int j = 0; j < 2; ++j) {
      int lb = (w * 128 + j * 64) * 8;
      gload16(pA + (size_t)j * 16 * lda + kt, &sA[lb]);
      gload16(pB + (size_t)j * 16 * ldb + kt, &sB[lb]);
    }
    __syncthreads();
    bf16x8 fa[4], fb[4];
    #pragma unroll
    for (int i = 0; i < 4; ++i) {
      fa[i] = *(const bf16x8*)&sA[(wr + i*16 + lr) * 32 + lk];
      fb[i] = *(const bf16x8*)&sB[(wc + i*16 + lr) * 32 + lk];
    }
    #pragma unroll
    for (int mi = 0; mi < 4; ++mi)
      #pragma unroll
      for (int ni = 0; ni < 4; ++ni)
        acc[mi][ni] = MFMA(fa[mi], fb[ni], acc[mi][ni]);
  }
  int crow = (lane >> 4) * 4, ccol = lane & 15;
  int base_e = ROUTED ? offs[e] : 0;
  int cnt_e  = ROUTED ? counts[e] : 0;
  #pragma unroll
  for (int mi = 0; mi < 4; ++mi)
  #pragma unroll
  for (int ni = 0; ni < 4; ++ni)
  #pragma unroll
  for (int r = 0; r < 4; ++r) {
    int row = row0 + wr + mi * 16 + crow + r;
    int col = n00 + wc + ni * 16 + ccol;
    size_t ci = (size_t)row * ldc + col;
    float v = acc[mi][ni][r];
    if (EPI == 4) {
      float wv = (row - base_e < cnt_e) ? epi[row] : 0.f;
      ((bf16*)Cp)[ci] = f2b(v * wv);
    } else if (EPI == 5) ((float*)Cp)[ci] += v;
  }
}

// ======== 128x128 LDS-staged GLU: H = silu(A@Wg^T) * (A@Wu^T), optional gather ========
template<bool ROUTED>
__global__ __launch_bounds__(256) void k_glu128(
    const bf16* __restrict__ A, int lda,
    const bf16* __restrict__ Wg, const bf16* __restrict__ Wu, int ldb, size_t estride,
    bf16* __restrict__ H, int ldc, int K,
    const int* __restrict__ offs, const int* __restrict__ toks,
    const int* __restrict__ counts)
{
  __shared__ __align__(16) bf16 sA[4096], sG[4096], sU[4096];
  int row0 = 0, e = 0;
  if (ROUTED) {
    int bid = blockIdx.x, cum = 0; e = -1;
    #pragma unroll
    for (int i = 0; i < 8; ++i) {
      int tiles = (offs[i+1] - offs[i]) >> 7;
      if (e < 0 && bid < cum + tiles) { e = i; row0 = offs[i] + ((bid - cum) << 7); }
      cum += tiles;
    }
    if (e < 0) return;
  } else {
    row0 = blockIdx.x * 128;
  }
  int tid = threadIdx.x;
  int lane = tid & 63, w = tid >> 6;
  int n00 = blockIdx.y * 128;
  int wr = (w >> 1) * 64, wc = (w & 1) * 64;
  int srow = w * 32 + (lane >> 2);
  int scol = (lane & 3) * 8;
  // per-lane A source rows (gathered if routed)
  size_t arow[2];
  #pragma unroll
  for (int j = 0; j < 2; ++j) {
    int r = row0 + srow + j * 16;
    if (ROUTED) {
      int tk = toks[r];
      if (r - offs[e] >= counts[e]) tk = 0;
      tk &= (Tz - 1);
      arow[j] = (size_t)tk * lda;
    } else {
      arow[j] = (size_t)r * lda;
    }
  }
  const bf16* wg = Wg + (size_t)e * estride;
  const bf16* wu = Wu + (size_t)e * estride;
  const bf16* pG = wg + (size_t)(n00 + srow) * ldb + scol;
  const bf16* pU = wu + (size_t)(n00 + srow) * ldb + scol;
  int lr = lane & 15, lk = (lane >> 4) * 8;
  f32x4 gg[4][4], uu[4][4];
  #pragma unroll
  for (int i = 0; i < 4; ++i)
    #pragma unroll
    for (int j = 0; j < 4; ++j) { gg[i][j] = {0.f,0.f,0.f,0.f}; uu[i][j] = gg[i][j]; }
  for (int kt = 0; kt < K; kt += 32) {
    if (kt) __syncthreads();
    #pragma unroll
    for (int j = 0; j < 2; ++j) {
      int lb = (w * 128 + j * 64) * 8;
      gload16(A + arow[j] + scol + kt, &sA[lb]);
      gload16(pG + (size_t)j * 16 * ldb + kt, &sG[lb]);
      gload16(pU + (size_t)j * 16 * ldb + kt, &sU[lb]);
    }
    __syncthreads();
    bf16x8 fa[4], fb[4];
    #pragma unroll
    for (int i = 0; i < 4; ++i) {
      fa[i] = *(const bf16x8*)&sA[(wr + i*16 + lr) * 32 + lk];
      fb[i] = *(const bf16x8*)&sG[(wc + i*16 + lr) * 32 + lk];
    }
    #pragma unroll
    for (int mi = 0; mi < 4; ++mi)
      #pragma unroll
      for (int ni = 0; ni < 4; ++ni)
        gg[mi][ni] = MFMA(fa[mi], fb[ni], gg[mi][ni]);
    #pragma unroll
    for (int i = 0; i < 4; ++i) fb[i] = *(const bf16x8*)&sU[(wc + i*16 + lr) * 32 + lk];
    #pragma unroll
    for (int mi = 0; mi < 4; ++mi)
      #pragma unroll
      for (int ni = 0; ni < 4; ++ni)
        uu[mi][ni] = MFMA(fa[mi], fb[ni], uu[mi][ni]);
  }
  int crow = (lane >> 4) * 4, ccol = lane & 15;
  #pragma unroll
  for (int mi = 0; mi < 4; ++mi)
  #pragma unroll
  for (int ni = 0; ni < 4; ++ni)
  #pragma unroll
  for (int r = 0; r < 4; ++r) {
    int row = row0 + wr + mi * 16 + crow + r;
    int col = n00 + wc + ni * 16 + ccol;
    float g = gg[mi][ni][r], u = uu[mi][ni][r];
    H[(size_t)row * ldc + col] = f2b(silu(g) * u);
  }
}

// ---------------- causal depthwise conv (4 taps) + silu; hi/lo in -> hi/lo out ----------------
__global__ __launch_bounds__(256) void k_conv(const bf16* __restrict__ xh, const bf16* __restrict__ xl,
                                              const float* __restrict__ cw, const float* __restrict__ cb,
                                              bf16* __restrict__ oh, bf16* __restrict__ ol){
  int d = blockIdx.x * 256 + threadIdx.x;   // [0,2048)
  int row = blockIdx.y;                     // [0,8192)
  int s = row & (Sz - 1);
  size_t base = (size_t)row * DIz + d;
  float w0 = cw[d*4+0], w1 = cw[d*4+1], w2 = cw[d*4+2], w3 = cw[d*4+3];
  float x0 = (s >= 3) ? rc(xh, xl, base - 3*DIz) : 0.f;
  float x1 = (s >= 2) ? rc(xh, xl, base - 2*DIz) : 0.f;
  float x2 = (s >= 1) ? rc(xh, xl, base - 1*DIz) : 0.f;
  float x3 = rc(xh, xl, base);
  float v = cb[d] + w0*x0 + w1*x1 + w2*x2 + w3*x3;
  float o = v / (1.f + expf(-v));
  split2(o, oh[base], ol[base]);
}

// ---------------- chunked selective scan, per d-half ----------------
__global__ __launch_bounds__(256) void k_scan1(const bf16* __restrict__ dth, const bf16* __restrict__ dtl,
                                               const bf16* __restrict__ xih, const bf16* __restrict__ xil,
                                               const bf16* __restrict__ xdh, const bf16* __restrict__ xdl,
                                               const float* __restrict__ A_log,
                                               float* __restrict__ P, float* __restrict__ R){
  int b = blockIdx.y, c = blockIdx.z;
  int d = blockIdx.x * 16 + (threadIdx.x >> 4);
  int n = threadIdx.x & 15;
  float Adn = -expf(A_log[d * DSz + n]);
  float h = 0.f, p = 1.f;
  int s0 = c * CLEN;
  #pragma unroll 2
  for (int s = s0; s < s0 + CLEN; ++s) {
    size_t row = (size_t)b * Sz + s;
    float dtv = rc(dth, dtl, row * NDH + d);
    float xiv = rc(xih, xil, row * DIz + d);
    float Bn  = rc(xdh, xdl, row * 128 + 64 + n);
    float da = expf(dtv * Adn);
    h = da * h + dtv * Bn * xiv;
    p *= da;
  }
  size_t idx = (((size_t)c * Bz + b) * NDH + d) * DSz + n;
  P[idx] = p; R[idx] = h;
}
__global__ __launch_bounds__(256) void k_scan2(const float* __restrict__ P, const float* __restrict__ R,
                                               float* __restrict__ Hin){
  int i = blockIdx.x * 256 + threadIdx.x;
  float h = 0.f;
  #pragma unroll
  for (int c = 0; c < NCHUNK; ++c) {
    size_t idx = (size_t)c * (Bz * NDH * DSz) + i;
    Hin[idx] = h;
    h = P[idx] * h + R[idx];
  }
}
__global__ __launch_bounds__(256) void k_scan3(const bf16* __restrict__ dth, const bf16* __restrict__ dtl,
                                               const bf16* __restrict__ xih, const bf16* __restrict__ xil,
                                               const bf16* __restrict__ xdh, const bf16* __restrict__ xdl,
                                               const bf16* __restrict__ resh, const bf16* __restrict__ resl,
                                               const float* __restrict__ A_log, const float* __restrict__ Dsk,
                                               const float* __restrict__ Hin,
                                               bf16* __restrict__ yh, bf16* __restrict__ yl){
  int b = blockIdx.y, c = blockIdx.z;
  int d = blockIdx.x * 16 + (threadIdx.x >> 4);
  int n = threadIdx.x & 15;
  float Adn = -expf(A_log[d * DSz + n]);
  float Dv = Dsk[d];
  size_t sidx = (((size_t)c * Bz + b) * NDH + d) * DSz + n;
  float h = Hin[sidx];
  int s0 = c * CLEN;
  for (int s = s0; s < s0 + CLEN; ++s) {
    size_t row = (size_t)b * Sz + s;
    float dtv = rc(dth, dtl, row * NDH + d);
    float xiv = rc(xih, xil, row * DIz + d);
    float Bn  = rc(xdh, xdl, row * 128 + 64 + n);
    float Cn  = rc(xdh, xdl, row * 128 + 80 + n);
    float da = expf(dtv * Adn);
    h = da * h + dtv * Bn * xiv;
    float p = h * Cn;
    p += __shfl_xor(p, 1); p += __shfl_xor(p, 2); p += __shfl_xor(p, 4); p += __shfl_xor(p, 8);
    if (n == 0) {
      float resv = rc(resh, resl, row * DIz + d);
      float yv = (p + xiv * Dv) * (resv / (1.f + expf(-resv)));
      split2(yv, yh[row * NDH + d], yl[row * NDH + d]);
    }
  }
}

// ---------------- MoE gate: inline fp32 rmsnorm + scores + softmax + top-2 ----------------
__global__ __launch_bounds__(64) void k_gate(const float* __restrict__ m, const float* __restrict__ nw,
                                             const float* __restrict__ gw, const float* __restrict__ gb,
                                             int* __restrict__ topi, float* __restrict__ topw,
                                             int* __restrict__ counts){
  int t = blockIdx.x;
  int lane = threadIdx.x;
  const float* xr = m + (size_t)t * Dz;
  float xv[16];
  float ss = 0.f;
  #pragma unroll
  for (int j = 0; j < 16; ++j) { xv[j] = xr[lane + j * 64]; ss += xv[j] * xv[j]; }
  #pragma unroll
  for (int o = 32; o; o >>= 1) ss += __shfl_xor(ss, o);
  float sc = rsqrtf(ss * (1.f / Dz) + 1e-6f);
  #pragma unroll
  for (int j = 0; j < 16; ++j) xv[j] *= sc * nw[lane + j * 64];
  float acc[8] = {0.f,0.f,0.f,0.f,0.f,0.f,0.f,0.f};
  #pragma unroll
  for (int j = 0; j < 16; ++j) {
    #pragma unroll
    for (int e = 0; e < 8; ++e) acc[e] += xv[j] * gw[e * Dz + lane + j * 64];
  }
  #pragma unroll
  for (int e = 0; e < 8; ++e) {
    float v = acc[e];
    #pragma unroll
    for (int o = 32; o; o >>= 1) v += __shfl_xor(v, o);
    acc[e] = v;
  }
  if (lane == 0) {
    float mx = acc[0];
    #pragma unroll
    for (int e = 1; e < 8; ++e) mx = fmaxf(mx, acc[e]);
    float scr[8]; float sum = 0.f;
    #pragma unroll
    for (int e = 0; e < 8; ++e) { scr[e] = expf(acc[e] - mx); sum += scr[e]; }
    float inv = 1.f / sum;
    #pragma unroll
    for (int e = 0; e < 8; ++e) scr[e] *= inv;
    int i0 = 0; float b0 = -1e30f;
    #pragma unroll
    for (int e = 0; e < 8; ++e) { float kv = scr[e] + gb[e]; if (kv > b0) { b0 = kv; i0 = e; } }
    int i1 = -1; float b1 = -1e30f;
    #pragma unroll
    for (int e = 0; e < 8; ++e) { if (e == i0) continue; float kv = scr[e] + gb[e]; if (kv > b1) { b1 = kv; i1 = e; } }
    float w0 = scr[i0], w1 = scr[i1];
    float wn = 1.f / (w0 + w1 + 1e-9f);
    topi[t*2] = i0; topi[t*2+1] = i1;
    topw[t*2] = w0 * wn; topw[t*2+1] = w1 * wn;
    atomicAdd(&counts[i0], 1); atomicAdd(&counts[i1], 1);
  }
}

__global__ void k_offs(const int* __restrict__ counts, int* __restrict__ offs, int* __restrict__ fill){
  if (threadIdx.x == 0) {
    int o = 0;
    for (int e = 0; e < 8; ++e) { offs[e] = o; o += ((counts[e] + 127) & ~127); }
    offs[8] = o;
  }
  if (threadIdx.x < 8) fill[threadIdx.x] = 0;
}

__global__ __launch_bounds__(256) void k_scatter(const int* __restrict__ topi, const float* __restrict__ topw,
                                                 const int* __restrict__ offs, int* __restrict__ fill,
                                                 int* __restrict__ toks, float* __restrict__ wslot,
                                                 int* __restrict__ slot_of){
  int i = blockIdx.x * 256 + threadIdx.x;
  if (i >= Tz * 2) return;
  int e = topi[i];
  int pos = atomicAdd(&fill[e], 1);
  int slot = offs[e] + pos;
  toks[slot] = i >> 1;
  wslot[slot] = topw[i];
  slot_of[i] = slot;
}

// ---------------- final combine: out = m + down0 + down1 ----------------
__global__ __launch_bounds__(256) void k_combine(const float* __restrict__ m,
                                                 const bf16* __restrict__ Hd, const int* __restrict__ slot_of,
                                                 float* __restrict__ out){
  int t = blockIdx.x;
  int ci = threadIdx.x * 4;
  int s0 = slot_of[t*2], s1 = slot_of[t*2+1];
  size_t base = (size_t)t * Dz + ci;
  float4 mv = *(const float4*)(m + base);
  ushort4 h0 = *(const ushort4*)((const unsigned short*)Hd + (size_t)s0 * Dz + ci);
  ushort4 h1 = *(const ushort4*)((const unsigned short*)Hd + (size_t)s1 * Dz + ci);
  out[base+0] = mv.x + us2f(h0.x) + us2f(h1.x);
  out[base+1] = mv.y + us2f(h0.y) + us2f(h1.y);
  out[base+2] = mv.z + us2f(h0.z) + us2f(h1.z);
  out[base+3] = mv.w + us2f(h0.w) + us2f(h1.w);
}

extern "C" void kernel_launch(void* const* d_in, const int* in_sizes, int n_in,
                              void* d_out, int out_size, void* d_ws, size_t ws_size,
                              hipStream_t stream) {
  (void)in_sizes; (void)n_in; (void)out_size;
  const float* x         = (const float*)d_in[0];
  const float* norm_w    = (const float*)d_in[1];
  const float* in_proj   = (const float*)d_in[2];
  const float* conv_w    = (const float*)d_in[3];
  const float* conv_b    = (const float*)d_in[4];
  const float* x_proj    = (const float*)d_in[5];
  const float* dt_proj   = (const float*)d_in[6];
  const float* dt_proj_b = (const float*)d_in[7];
  const float* A_log     = (const float*)d_in[8];
  const float* D_skip    = (const float*)d_in[9];
  const float* out_proj  = (const float*)d_in[10];
  const float* gate_w    = (const float*)d_in[11];
  const float* gate_b    = (const float*)d_in[12];
  const float* w_gate    = (const float*)d_in[13];
  const float* w_up      = (const float*)d_in[14];
  const float* w_down    = (const float*)d_in[15];
  const float* ws_gate   = (const float*)d_in[16];
  const float* ws_up     = (const float*)d_in[17];
  const float* ws_down   = (const float*)d_in[18];
  float* out = (float*)d_out;

  const size_t MB = 1024 * 1024;
  const size_t NEED = 251 * MB;
  if (ws_size < NEED) {
    k_fill<<<dim3(1), dim3(256), 0, stream>>>(out, (float)(ws_size / MB));
    fprintf(stderr, "kernel_launch: ws_size=%zu < needed=%zu\n", ws_size, NEED);
    return;
  }
  char* P = (char*)d_ws;
  // ---- phase A (mamba, split precision, two d-halves for scan) ----
  bf16* res_h = (bf16*)(P + 0*MB);     // [8192,2048] 32MB
  bf16* res_l = (bf16*)(P + 32*MB);
  bf16* xi_h  = (bf16*)(P + 64*MB);    // [8192,2048] 32MB
  bf16* xi_l  = (bf16*)(P + 96*MB);
  bf16* xd_h  = (bf16*)(P + 128*MB);   // [8192,128] 2MB
  bf16* xd_l  = (bf16*)(P + 130*MB);
  bf16* dth   = (bf16*)(P + 132*MB);   // [8192,1024] 16MB per-half
  bf16* dtl   = (bf16*)(P + 148*MB);
  float* scanP = (float*)(P + 164*MB); // 2MB each
  float* scanR = (float*)(P + 166*MB);
  float* scanH = (float*)(P + 168*MB);
  bf16* y_h   = (bf16*)(P + 176*MB);   // [8192,1024] 16MB per-half
  bf16* y_l   = (bf16*)(P + 192*MB);
  float* mbuf = (float*)(P + 208*MB);  // [8192,1024] f32 32MB (persists)
  // prologue staging (dead before the scan loop):
  bf16* nrm_h = (bf16*)(P + 128*MB);
  bf16* nrm_l = (bf16*)(P + 144*MB);
  bf16* iph   = (bf16*)(P + 160*MB);
  bf16* ipl   = (bf16*)(P + 168*MB);
  bf16* xzi_h = (bf16*)(P + 176*MB);
  bf16* xzi_l = (bf16*)(P + 208*MB);
  // persistent small weights (240..250)
  bf16* xph   = (bf16*)(P + 240*MB);
  bf16* xpl   = (bf16*)(P + 240*MB + 512*1024);
  bf16* dph   = (bf16*)(P + 241*MB);
  bf16* dpl   = (bf16*)(P + 241*MB + 256*1024);
  bf16* oph   = (bf16*)(P + 242*MB);
  bf16* opl   = (bf16*)(P + 246*MB);
  // ---- phase B (MoE) overlay ----
  bf16* n2b   = (bf16*)(P + 0*MB);     // 16MB
  bf16* wgh   = (bf16*)(P + 16*MB);    // 16MB
  bf16* wuh   = (bf16*)(P + 32*MB);
  bf16* wdh   = (bf16*)(P + 48*MB);
  bf16* wsg   = (bf16*)(P + 64*MB);    // 4MB
  bf16* wsu   = (bf16*)(P + 68*MB);
  bf16* wsd   = (bf16*)(P + 72*MB);
  bf16* Hbuf  = (bf16*)(P + 76*MB);    // [17408,1024] 34MB
  bf16* Hd    = (bf16*)(P + 111*MB);   // 34MB
  bf16* Sh    = (bf16*)(P + 146*MB);   // [8192,2048] 32MB
  char* Rt    = P + 250*MB;
  int*   counts  = (int*)(Rt);
  int*   offsb   = (int*)(Rt + 64);
  int*   fill    = (int*)(Rt + 128);
  int*   topi    = (int*)(Rt + 1024);
  float* topw    = (float*)(Rt + 1024 + 65536);
  int*   toks    = (int*)(Rt + 1024 + 2*65536);
  float* wslot   = (float*)(Rt + 1024 + 2*65536 + 69632);
  int*   slot_of = (int*)(Rt + 1024 + 2*65536 + 2*69632);

  auto spw = [&](const float* s, bf16* dh, bf16* dl, size_t n){
    k_split<<<dim3((unsigned)((n/4 + 255)/256)), dim3(256), 0, stream>>>(s, dh, dl, (int)n);
  };
  auto cvt = [&](const float* s, bf16* d, size_t n){
    k_f2bf<<<dim3((unsigned)((n/4 + 255)/256)), dim3(256), 0, stream>>>(s, d, (int)n);
  };

  // mamba weight splits
  spw(in_proj,  iph, ipl, (size_t)4096*1024);
  spw(dt_proj,  dph, dpl, (size_t)2048*64);
  spw(out_proj, oph, opl, (size_t)1024*2048);
  k_split_pad<<<dim3(256), dim3(256), 0, stream>>>(x_proj, xph, xpl);

  // 1. rmsnorm(x) -> normed hi/lo
  k_rmsnorm<true><<<dim3(Tz), dim3(256), 0, stream>>>(x, norm_w, nrm_h, nrm_l);
  // 2. in_proj (split, 128-tile LDS): dual store -> xzi / res
  k_gemm_sp128<1><<<dim3(Tz/128, 4096/128), dim3(256), 0, stream>>>(
      nrm_h, nrm_l, Dz, iph, ipl, Dz, xzi_h, xzi_l, res_h, res_l, nullptr, 0, Dz, nullptr);
  // 3. causal conv + silu -> xi hi/lo
  k_conv<<<dim3(DIz/256, Tz), dim3(256), 0, stream>>>(xzi_h, xzi_l, conv_w, conv_b, xi_h, xi_l);
  // 4. x_proj (split, naive small) -> xdbl hi/lo
  k_gemm_sp<0><<<dim3(Tz/64, 128/64), dim3(256), 0, stream>>>(
      xi_h, xi_l, DIz, xph, xpl, DIz, xd_h, xd_l, nullptr, 128, DIz, nullptr);

  // 5-7. per d-half: dt_proj -> scan -> out_proj partial
  for (int h = 0; h < 2; ++h) {
    int d0 = h * NDH;
    k_gemm_sp<2><<<dim3(Tz/64, NDH/64), dim3(256), 0, stream>>>(
        xd_h, xd_l, 128, dph + (size_t)d0*DTRz, dpl + (size_t)d0*DTRz, DTRz,
        dth, dtl, nullptr, NDH, DTRz, dt_proj_b + d0);
    k_scan1<<<dim3(NDH/16, Bz, NCHUNK), dim3(256), 0, stream>>>(
        dth, dtl, xi_h + d0, xi_l + d0, xd_h, xd_l, A_log + (size_t)d0*DSz, scanP, scanR);
    k_scan2<<<dim3(Bz*NDH*DSz/256), dim3(256), 0, stream>>>(scanP, scanR, scanH);
    k_scan3<<<dim3(NDH/16, Bz, NCHUNK), dim3(256), 0, stream>>>(
        dth, dtl, xi_h + d0, xi_l + d0, xd_h, xd_l, res_h + d0, res_l + d0,
        A_log + (size_t)d0*DSz, D_skip + d0, scanH, y_h, y_l);
    if (h == 0)
      k_gemm_sp128<3><<<dim3(Tz/128, Dz/128), dim3(256), 0, stream>>>(
          y_h, y_l, NDH, oph + d0, opl + d0, DIz, nullptr, nullptr, nullptr, nullptr,
          mbuf, Dz, NDH, x);
    else
      k_gemm_sp128<4><<<dim3(Tz/128, Dz/128), dim3(256), 0, stream>>>(
          y_h, y_l, NDH, oph + d0, opl + d0, DIz, nullptr, nullptr, nullptr, nullptr,
          mbuf, Dz, NDH, nullptr);
  }

  // MoE weight conversion (plain bf16)
  cvt(w_gate,   wgh, (size_t)8*1024*1024);
  cvt(w_up,     wuh, (size_t)8*1024*1024);
  cvt(w_down,   wdh, (size_t)8*1024*1024);
  cvt(ws_gate,  wsg, (size_t)2048*1024);
  cvt(ws_up,    wsu, (size_t)2048*1024);
  cvt(ws_down,  wsd, (size_t)1024*2048);
  // 8. rmsnorm(m) -> n2 bf16
  k_rmsnorm<false><<<dim3(Tz), dim3(256), 0, stream>>>(mbuf, norm_w, n2b, nullptr);
  // 9. gate + routing
  k_zero_counts<<<dim3(1), dim3(64), 0, stream>>>(counts);
  k_gate<<<dim3(Tz), dim3(64), 0, stream>>>(mbuf, norm_w, gate_w, gate_b, topi, topw, counts);
  k_offs<<<dim3(1), dim3(64), 0, stream>>>(counts, offsb, fill);
  k_scatter<<<dim3(Tz*2/256), dim3(256), 0, stream>>>(topi, topw, offsb, fill, toks, wslot, slot_of);
  // 10. routed experts: GLU then down (scaled by gate weight)
  k_glu128<true><<<dim3(SLOTCAP/128, Fz/128), dim3(256), 0, stream>>>(
      n2b, Dz, wgh, wuh, Dz, (size_t)Fz*Dz, Hbuf, Fz, Dz, offsb, toks, counts);
  k_gemm128<4,true><<<dim3(SLOTCAP/128, Dz/128), dim3(256), 0, stream>>>(
      Hbuf, Fz, wdh, Fz, (size_t)Dz*Fz, Hd, Dz, Fz, wslot, offsb, counts);
  // 11. shared expert GLU -> Sh
  k_glu128<false><<<dim3(Tz/128, FSz/128), dim3(256), 0, stream>>>(
      n2b, Dz, wsg, wsu, Dz, 0, Sh, FSz, Dz, nullptr, nullptr, nullptr);
  // 12. combine -> out = m + routed
  k_combine<<<dim3(Tz), dim3(256), 0, stream>>>(mbuf, Hd, slot_of, out);
  // 13. shared down: out += Sh @ ws_down^T
  k_gemm128<5,false><<<dim3(Tz/128, Dz/128), dim3(256), 0, stream>>>(
      Sh, FSz, wsd, FSz, 0, out, Dz, FSz, nullptr, nullptr, nullptr);
}

// Round 6
// 1514.481 us; speedup vs baseline: 2.6683x; 1.4953x over previous
//
#include <hip/hip_runtime.h>
#include <hip/hip_bf16.h>
#include <cstdio>

#define Bz 2
#define Sz 4096
#define Dz 1024
#define DIz 2048
#define DSz 16
#define DTRz 64
#define NE 8
#define Fz 1024
#define FSz 2048
#define Tz (Bz*Sz)            // 8192 tokens
#define NDH 1024              // d-half width
#define NCH2 64
#define CL2 (Sz/NCH2)         // 64
#define SLOTCAP 17408         // 136 tiles * 128

typedef __hip_bfloat16 bf16;
typedef short bf16x8 __attribute__((ext_vector_type(8)));
typedef float f32x4 __attribute__((ext_vector_type(4)));

#define MFMA(a,b,c) __builtin_amdgcn_mfma_f32_16x16x32_bf16(a,b,c,0,0,0)

__device__ __forceinline__ float b2f(bf16 v){ return __bfloat162float(v); }
__device__ __forceinline__ bf16  f2b(float v){ return __float2bfloat16(v); }
__device__ __forceinline__ float us2f(unsigned short u){
  union { unsigned int i; float f; } v; v.i = ((unsigned int)u) << 16; return v.f;
}
__device__ __forceinline__ float silu(float v){ return v / (1.f + __expf(-v)); }
__device__ __forceinline__ void split2(float v, bf16& h, bf16& l){ h = f2b(v); l = f2b(v - b2f(h)); }
__device__ __forceinline__ float rc(const bf16* __restrict__ h, const bf16* __restrict__ l, size_t i){
  return b2f(h[i]) + b2f(l[i]);
}
__device__ __forceinline__ void gload16(const bf16* g, bf16* l){
  __builtin_amdgcn_global_load_lds(
      (const __attribute__((address_space(1))) void*)g,
      (__attribute__((address_space(3))) void*)l, 16, 0, 0);
}

// ---------------- guard diagnostic ----------------
__global__ void k_fill(float* __restrict__ o, float v){ o[threadIdx.x] = v; }

// ---------------- weight conversion ----------------
__global__ __launch_bounds__(256) void k_f2bf(const float* __restrict__ s, bf16* __restrict__ d, int n){
  int i = (blockIdx.x * 256 + threadIdx.x) * 4;
  if (i + 3 < n) {
    float4 v = *(const float4*)(s + i);
    d[i] = f2b(v.x); d[i+1] = f2b(v.y); d[i+2] = f2b(v.z); d[i+3] = f2b(v.w);
  }
}
__global__ __launch_bounds__(256) void k_split(const float* __restrict__ s, bf16* __restrict__ dh,
                                               bf16* __restrict__ dl, int n){
  int i = (blockIdx.x * 256 + threadIdx.x) * 4;
  if (i + 3 < n) {
    float4 v = *(const float4*)(s + i);
    split2(v.x, dh[i],   dl[i]);
    split2(v.y, dh[i+1], dl[i+1]);
    split2(v.z, dh[i+2], dl[i+2]);
    split2(v.w, dh[i+3], dl[i+3]);
  }
}
// x_proj [96,2048] -> padded [128,2048] hi/lo (pad rows = 0)
__global__ __launch_bounds__(256) void k_split_pad(const float* __restrict__ s, bf16* __restrict__ dh,
                                                   bf16* __restrict__ dl){
  int i = (blockIdx.x * 256 + threadIdx.x) * 4;
  int row = i >> 11;
  if (row < 96) {
    float4 v = *(const float4*)(s + i);
    split2(v.x, dh[i],   dl[i]);
    split2(v.y, dh[i+1], dl[i+1]);
    split2(v.z, dh[i+2], dl[i+2]);
    split2(v.w, dh[i+3], dl[i+3]);
  } else {
    bf16 z = f2b(0.f);
    dh[i]=z; dh[i+1]=z; dh[i+2]=z; dh[i+3]=z;
    dl[i]=z; dl[i+1]=z; dl[i+2]=z; dl[i+3]=z;
  }
}

__global__ void k_zero_counts(int* __restrict__ c){
  if (threadIdx.x < NE) c[threadIdx.x] = 0;
}

// ---------------- rmsnorm (f32 in). HL: hi/lo out; else single bf16 out ----------------
template<bool HL>
__global__ __launch_bounds__(256) void k_rmsnorm(const float* __restrict__ x, const float* __restrict__ w,
                                                 bf16* __restrict__ oh, bf16* __restrict__ ol){
  int row = blockIdx.x;
  const float* xr = x + (size_t)row * Dz;
  int c4 = threadIdx.x * 4;
  float4 v = *(const float4*)(xr + c4);
  float ss = v.x*v.x + v.y*v.y + v.z*v.z + v.w*v.w;
  #pragma unroll
  for (int o = 32; o; o >>= 1) ss += __shfl_xor(ss, o);
  __shared__ float sred[4];
  if ((threadIdx.x & 63) == 0) sred[threadIdx.x >> 6] = ss;
  __syncthreads();
  float tot = sred[0] + sred[1] + sred[2] + sred[3];
  float sc = rsqrtf(tot * (1.f / Dz) + 1e-6f);
  float4 wv = *(const float4*)(w + c4);
  float o0 = v.x*sc*wv.x, o1 = v.y*sc*wv.y, o2 = v.z*sc*wv.z, o3 = v.w*sc*wv.w;
  size_t ci = (size_t)row * Dz + c4;
  if (HL) {
    split2(o0, oh[ci], ol[ci]);   split2(o1, oh[ci+1], ol[ci+1]);
    split2(o2, oh[ci+2], ol[ci+2]); split2(o3, oh[ci+3], ol[ci+3]);
  } else {
    oh[ci] = f2b(o0); oh[ci+1] = f2b(o1); oh[ci+2] = f2b(o2); oh[ci+3] = f2b(o3);
  }
}

// ======== naive 64x64 split GEMM for small shapes ========
// EPI 5: Cf[row*ldc+col] = softplus(v+epi[col])  (dt_proj)
// EPI 6: hi/lo store to C1h/C1l (ldc); cols [64,96) also f32 -> Cf[row*32+col-64] (x_proj)
template<int EPI>
__global__ __launch_bounds__(256) void k_gemm_sp(
    const bf16* __restrict__ Ah, const bf16* __restrict__ Al, int lda,
    const bf16* __restrict__ Bh, const bf16* __restrict__ Bl, int ldb,
    bf16* __restrict__ C1h, bf16* __restrict__ C1l,
    float* __restrict__ Cf, int ldc, int K,
    const float* __restrict__ epi)
{
  int row0 = blockIdx.x * 64;
  int lane = threadIdx.x & 63, wid = threadIdx.x >> 6;
  int m0 = row0 + (wid >> 1) * 32;
  int n0 = blockIdx.y * 64 + (wid & 1) * 32;
  int lr = lane & 15, lk = (lane >> 4) * 8;
  const bf16 *pah0 = Ah + (size_t)(m0+lr)*lda + lk, *pah1 = pah0 + (size_t)16*lda;
  const bf16 *pal0 = Al + (size_t)(m0+lr)*lda + lk, *pal1 = pal0 + (size_t)16*lda;
  const bf16 *pbh0 = Bh + (size_t)(n0+lr)*ldb + lk, *pbh1 = pbh0 + (size_t)16*ldb;
  const bf16 *pbl0 = Bl + (size_t)(n0+lr)*ldb + lk, *pbl1 = pbl0 + (size_t)16*ldb;
  f32x4 a00 = {0.f,0.f,0.f,0.f}, a01 = a00, a10 = a00, a11 = a00;
  for (int k = 0; k < K; k += 32) {
    bf16x8 AH0 = *(const bf16x8*)pah0, AH1 = *(const bf16x8*)pah1;
    bf16x8 AL0 = *(const bf16x8*)pal0, AL1 = *(const bf16x8*)pal1;
    bf16x8 BH0 = *(const bf16x8*)pbh0, BH1 = *(const bf16x8*)pbh1;
    bf16x8 BL0 = *(const bf16x8*)pbl0, BL1 = *(const bf16x8*)pbl1;
    a00 = MFMA(AH0, BH0, a00); a00 = MFMA(AH0, BL0, a00); a00 = MFMA(AL0, BH0, a00);
    a01 = MFMA(AH0, BH1, a01); a01 = MFMA(AH0, BL1, a01); a01 = MFMA(AL0, BH1, a01);
    a10 = MFMA(AH1, BH0, a10); a10 = MFMA(AH1, BL0, a10); a10 = MFMA(AL1, BH0, a10);
    a11 = MFMA(AH1, BH1, a11); a11 = MFMA(AH1, BL1, a11); a11 = MFMA(AL1, BH1, a11);
    pah0 += 32; pah1 += 32; pal0 += 32; pal1 += 32;
    pbh0 += 32; pbh1 += 32; pbl0 += 32; pbl1 += 32;
  }
  int crow = (lane >> 4) * 4, ccol = lane & 15;
  f32x4 accs[2][2] = {{a00, a01}, {a10, a11}};
  #pragma unroll
  for (int mi = 0; mi < 2; ++mi)
  #pragma unroll
  for (int ni = 0; ni < 2; ++ni)
  #pragma unroll
  for (int r = 0; r < 4; ++r) {
    int row = m0 + mi * 16 + crow + r;
    int col = n0 + ni * 16 + ccol;
    float v = accs[mi][ni][r];
    if (EPI == 5) {
      float t = v + epi[col];
      Cf[(size_t)row * ldc + col] = (t > 20.f) ? t : log1pf(__expf(t));
    } else if (EPI == 6) {
      size_t ci = (size_t)row * ldc + col;
      split2(v, C1h[ci], C1l[ci]);
      if (col >= 64 && col < 96) Cf[(size_t)row * 32 + col - 64] = v;
    }
  }
}

// ======== 128x128 LDS-staged split GEMM (3-term) ========
// EPI 1: dual f32 store: col<2048 -> Cf, else Cf2 (inner ld 2048)   (in_proj)
// EPI 3: Cf = v + epi[ci]; EPI 4: Cf += v                           (out_proj)
template<int EPI>
__global__ __launch_bounds__(256) void k_gemm_sp128(
    const bf16* __restrict__ Ah, const bf16* __restrict__ Al, int lda,
    const bf16* __restrict__ Bh, const bf16* __restrict__ Bl, int ldb,
    float* __restrict__ Cf, float* __restrict__ Cf2, int ldc, int K,
    const float* __restrict__ epi)
{
  __shared__ __align__(16) bf16 sAh[4096], sAl[4096], sBh[4096], sBl[4096];
  int tid = threadIdx.x;
  int lane = tid & 63, w = tid >> 6;
  int row0 = blockIdx.x * 128, n00 = blockIdx.y * 128;
  int wr = (w >> 1) * 64, wc = (w & 1) * 64;
  int srow = w * 32 + (lane >> 2);
  int scol = (lane & 3) * 8;
  const bf16* pAh = Ah + (size_t)(row0 + srow) * lda + scol;
  const bf16* pAl = Al + (size_t)(row0 + srow) * lda + scol;
  const bf16* pBh = Bh + (size_t)(n00 + srow) * ldb + scol;
  const bf16* pBl = Bl + (size_t)(n00 + srow) * ldb + scol;
  int lr = lane & 15, lk = (lane >> 4) * 8;
  f32x4 acc[4][4];
  #pragma unroll
  for (int i = 0; i < 4; ++i)
    #pragma unroll
    for (int j = 0; j < 4; ++j) acc[i][j] = {0.f,0.f,0.f,0.f};
  for (int kt = 0; kt < K; kt += 32) {
    if (kt) __syncthreads();
    #pragma unroll
    for (int j = 0; j < 2; ++j) {
      int lb = (w * 128 + j * 64) * 8;
      size_t goa = (size_t)j * 16 * lda + kt;
      size_t gob = (size_t)j * 16 * ldb + kt;
      gload16(pAh + goa, &sAh[lb]);
      gload16(pAl + goa, &sAl[lb]);
      gload16(pBh + gob, &sBh[lb]);
      gload16(pBl + gob, &sBl[lb]);
    }
    __syncthreads();
    bf16x8 fa[4], fb[4], ft[4];
    #pragma unroll
    for (int i = 0; i < 4; ++i) {
      fa[i] = *(const bf16x8*)&sAh[(wr + i*16 + lr) * 32 + lk];
      fb[i] = *(const bf16x8*)&sBh[(wc + i*16 + lr) * 32 + lk];
    }
    #pragma unroll
    for (int mi = 0; mi < 4; ++mi)
      #pragma unroll
      for (int ni = 0; ni < 4; ++ni)
        acc[mi][ni] = MFMA(fa[mi], fb[ni], acc[mi][ni]);
    #pragma unroll
    for (int i = 0; i < 4; ++i) ft[i] = *(const bf16x8*)&sBl[(wc + i*16 + lr) * 32 + lk];
    #pragma unroll
    for (int mi = 0; mi < 4; ++mi)
      #pragma unroll
      for (int ni = 0; ni < 4; ++ni)
        acc[mi][ni] = MFMA(fa[mi], ft[ni], acc[mi][ni]);
    #pragma unroll
    for (int i = 0; i < 4; ++i) ft[i] = *(const bf16x8*)&sAl[(wr + i*16 + lr) * 32 + lk];
    #pragma unroll
    for (int mi = 0; mi < 4; ++mi)
      #pragma unroll
      for (int ni = 0; ni < 4; ++ni)
        acc[mi][ni] = MFMA(ft[mi], fb[ni], acc[mi][ni]);
  }
  int crow = (lane >> 4) * 4, ccol = lane & 15;
  #pragma unroll
  for (int mi = 0; mi < 4; ++mi)
  #pragma unroll
  for (int ni = 0; ni < 4; ++ni)
  #pragma unroll
  for (int r = 0; r < 4; ++r) {
    int row = row0 + wr + mi * 16 + crow + r;
    int col = n00 + wc + ni * 16 + ccol;
    float v = acc[mi][ni][r];
    if (EPI == 1) {
      size_t ci = (size_t)row * 2048 + (col & 2047);
      if (col < 2048) Cf[ci] = v; else Cf2[ci] = v;
    } else if (EPI == 3) {
      size_t ci = (size_t)row * ldc + col;
      Cf[ci] = v + epi[ci];
    } else if (EPI == 4) {
      size_t ci = (size_t)row * ldc + col;
      Cf[ci] += v;
    }
  }
}

// ======== 128x128 LDS-staged plain GEMM. EPI 4 = v*wslot[row] (guarded) -> bf16, 5 = f32 += ========
template<int EPI, bool ROUTED>
__global__ __launch_bounds__(256) void k_gemm128(
    const bf16* __restrict__ A, int lda,
    const bf16* __restrict__ Bw, int ldb, size_t estride,
    void* __restrict__ Cp, int ldc, int K,
    const float* __restrict__ epi,
    const int* __restrict__ offs, const int* __restrict__ counts)
{
  __shared__ __align__(16) bf16 sA[4096], sB[4096];
  int row0 = 0, e = 0;
  if (ROUTED) {
    int bid = blockIdx.x, cum = 0; e = -1;
    #pragma unroll
    for (int i = 0; i < 8; ++i) {
      int tiles = (offs[i+1] - offs[i]) >> 7;
      if (e < 0 && bid < cum + tiles) { e = i; row0 = offs[i] + ((bid - cum) << 7); }
      cum += tiles;
    }
    if (e < 0) return;
  } else {
    row0 = blockIdx.x * 128;
  }
  const bf16* Bm = Bw + (size_t)e * estride;
  int tid = threadIdx.x;
  int lane = tid & 63, w = tid >> 6;
  int n00 = blockIdx.y * 128;
  int wr = (w >> 1) * 64, wc = (w & 1) * 64;
  int srow = w * 32 + (lane >> 2);
  int scol = (lane & 3) * 8;
  const bf16* pA = A + (size_t)(row0 + srow) * lda + scol;
  const bf16* pB = Bm + (size_t)(n00 + srow) * ldb + scol;
  int lr = lane & 15, lk = (lane >> 4) * 8;
  f32x4 acc[4][4];
  #pragma unroll
  for (int i = 0; i < 4; ++i)
    #pragma unroll
    for (int j = 0; j < 4; ++j) acc[i][j] = {0.f,0.f,0.f,0.f};
  for (int kt = 0; kt < K; kt += 32) {
    if (kt) __syncthreads();
    #pragma unroll
    for (int j = 0; j < 2; ++j) {
      int lb = (w * 128 + j * 64) * 8;
      gload16(pA + (size_t)j * 16 * lda + kt, &sA[lb]);
      gload16(pB + (size_t)j * 16 * ldb + kt, &sB[lb]);
    }
    __syncthreads();
    bf16x8 fa[4], fb[4];
    #pragma unroll
    for (int i = 0; i < 4; ++i) {
      fa[i] = *(const bf16x8*)&sA[(wr + i*16 + lr) * 32 + lk];
      fb[i] = *(const bf16x8*)&sB[(wc + i*16 + lr) * 32 + lk];
    }
    #pragma unroll
    for (int mi = 0; mi < 4; ++mi)
      #pragma unroll
      for (int ni = 0; ni < 4; ++ni)
        acc[mi][ni] = MFMA(fa[mi], fb[ni], acc[mi][ni]);
  }
  int crow = (lane >> 4) * 4, ccol = lane & 15;
  int base_e = ROUTED ? offs[e] : 0;
  int cnt_e  = ROUTED ? counts[e] : 0;
  #pragma unroll
  for (int mi = 0; mi < 4; ++mi)
  #pragma unroll
  for (int ni = 0; ni < 4; ++ni)
  #pragma unroll
  for (int r = 0; r < 4; ++r) {
    int row = row0 + wr + mi * 16 + crow + r;
    int col = n00 + wc + ni * 16 + ccol;
    size_t ci = (size_t)row * ldc + col;
    float v = acc[mi][ni][r];
    if (EPI == 4) {
      float wv = (row - base_e < cnt_e) ? epi[row] : 0.f;
      ((bf16*)Cp)[ci] = f2b(v * wv);
    } else if (EPI == 5) ((float*)Cp)[ci] += v;
  }
}

// ======== 128x128 LDS-staged GLU: H = silu(A@Wg^T) * (A@Wu^T), optional gather ========
template<bool ROUTED>
__global__ __launch_bounds__(256) void k_glu128(
    const bf16* __restrict__ A, int lda,
    const bf16* __restrict__ Wg, const bf16* __restrict__ Wu, int ldb, size_t estride,
    bf16* __restrict__ H, int ldc, int K,
    const int* __restrict__ offs, const int* __restrict__ toks,
    const int* __restrict__ counts)
{
  __shared__ __align__(16) bf16 sA[4096], sG[4096], sU[4096];
  int row0 = 0, e = 0;
  if (ROUTED) {
    int bid = blockIdx.x, cum = 0; e = -1;
    #pragma unroll
    for (int i = 0; i < 8; ++i) {
      int tiles = (offs[i+1] - offs[i]) >> 7;
      if (e < 0 && bid < cum + tiles) { e = i; row0 = offs[i] + ((bid - cum) << 7); }
      cum += tiles;
    }
    if (e < 0) return;
  } else {
    row0 = blockIdx.x * 128;
  }
  int tid = threadIdx.x;
  int lane = tid & 63, w = tid >> 6;
  int n00 = blockIdx.y * 128;
  int wr = (w >> 1) * 64, wc = (w & 1) * 64;
  int srow = w * 32 + (lane >> 2);
  int scol = (lane & 3) * 8;
  size_t arow[2];
  #pragma unroll
  for (int j = 0; j < 2; ++j) {
    int r = row0 + srow + j * 16;
    if (ROUTED) {
      int tk = toks[r];
      if (r - offs[e] >= counts[e]) tk = 0;
      tk &= (Tz - 1);
      arow[j] = (size_t)tk * lda;
    } else {
      arow[j] = (size_t)r * lda;
    }
  }
  const bf16* wg = Wg + (size_t)e * estride;
  const bf16* wu = Wu + (size_t)e * estride;
  const bf16* pG = wg + (size_t)(n00 + srow) * ldb + scol;
  const bf16* pU = wu + (size_t)(n00 + srow) * ldb + scol;
  int lr = lane & 15, lk = (lane >> 4) * 8;
  f32x4 gg[4][4], uu[4][4];
  #pragma unroll
  for (int i = 0; i < 4; ++i)
    #pragma unroll
    for (int j = 0; j < 4; ++j) { gg[i][j] = {0.f,0.f,0.f,0.f}; uu[i][j] = gg[i][j]; }
  for (int kt = 0; kt < K; kt += 32) {
    if (kt) __syncthreads();
    #pragma unroll
    for (int j = 0; j < 2; ++j) {
      int lb = (w * 128 + j * 64) * 8;
      gload16(A + arow[j] + scol + kt, &sA[lb]);
      gload16(pG + (size_t)j * 16 * ldb + kt, &sG[lb]);
      gload16(pU + (size_t)j * 16 * ldb + kt, &sU[lb]);
    }
    __syncthreads();
    bf16x8 fa[4], fb[4];
    #pragma unroll
    for (int i = 0; i < 4; ++i) {
      fa[i] = *(const bf16x8*)&sA[(wr + i*16 + lr) * 32 + lk];
      fb[i] = *(const bf16x8*)&sG[(wc + i*16 + lr) * 32 + lk];
    }
    #pragma unroll
    for (int mi = 0; mi < 4; ++mi)
      #pragma unroll
      for (int ni = 0; ni < 4; ++ni)
        gg[mi][ni] = MFMA(fa[mi], fb[ni], gg[mi][ni]);
    #pragma unroll
    for (int i = 0; i < 4; ++i) fb[i] = *(const bf16x8*)&sU[(wc + i*16 + lr) * 32 + lk];
    #pragma unroll
    for (int mi = 0; mi < 4; ++mi)
      #pragma unroll
      for (int ni = 0; ni < 4; ++ni)
        uu[mi][ni] = MFMA(fa[mi], fb[ni], uu[mi][ni]);
  }
  int crow = (lane >> 4) * 4, ccol = lane & 15;
  #pragma unroll
  for (int mi = 0; mi < 4; ++mi)
  #pragma unroll
  for (int ni = 0; ni < 4; ++ni)
  #pragma unroll
  for (int r = 0; r < 4; ++r) {
    int row = row0 + wr + mi * 16 + crow + r;
    int col = n00 + wc + ni * 16 + ccol;
    float g = gg[mi][ni][r], u = uu[mi][ni][r];
    H[(size_t)row * ldc + col] = f2b(silu(g) * u);
  }
}

// ---------------- causal depthwise conv (4 taps) + silu; f32 in -> hi/lo out ----------------
__global__ __launch_bounds__(256) void k_conv(const float* __restrict__ xz,
                                              const float* __restrict__ cw, const float* __restrict__ cb,
                                              bf16* __restrict__ oh, bf16* __restrict__ ol){
  int d = blockIdx.x * 256 + threadIdx.x;   // [0,2048)
  int row = blockIdx.y;                     // [0,8192)
  int s = row & (Sz - 1);
  size_t base = (size_t)row * DIz + d;
  float w0 = cw[d*4+0], w1 = cw[d*4+1], w2 = cw[d*4+2], w3 = cw[d*4+3];
  float x0 = (s >= 3) ? xz[base - 3*DIz] : 0.f;
  float x1 = (s >= 2) ? xz[base - 2*DIz] : 0.f;
  float x2 = (s >= 1) ? xz[base - 1*DIz] : 0.f;
  float x3 = xz[base];
  float v = cb[d] + w0*x0 + w1*x1 + w2*x2 + w3*x3;
  float o = v / (1.f + __expf(-v));
  split2(o, oh[base], ol[base]);
}

// ---------------- chunked selective scan: thread-per-d, h[16] in registers ----------------
// dtf: [Tz,NDH] f32. xih/xil pre-offset by d0 (ld DIz). xdf: [Tz,32] f32 (B|C). A_log pre-offset d0*16.
__global__ __launch_bounds__(256) void k_scan1r(const float* __restrict__ dtf,
                                                const bf16* __restrict__ xih, const bf16* __restrict__ xil,
                                                const float* __restrict__ xdf, const float* __restrict__ A_log,
                                                float* __restrict__ P, float* __restrict__ R){
  int b = blockIdx.y, c = blockIdx.z;
  int d = blockIdx.x * 256 + threadIdx.x;   // [0,NDH)
  __shared__ float sBC[CL2*32];             // 8KB
  int s0 = c * CL2;
  for (int i = threadIdx.x; i < CL2*32; i += 256)
    sBC[i] = xdf[((size_t)b*Sz + s0 + (i >> 5)) * 32 + (i & 31)];
  float Adn[16];
  #pragma unroll
  for (int n = 0; n < 16; ++n) Adn[n] = -__expf(A_log[d*16+n]);
  __syncthreads();
  float h[16];
  #pragma unroll
  for (int n = 0; n < 16; ++n) h[n] = 0.f;
  float sdt = 0.f;
  for (int s = 0; s < CL2; ++s) {
    size_t row = (size_t)b * Sz + s0 + s;
    float dtv = dtf[row * NDH + d];
    float xiv = rc(xih, xil, row * DIz + d);
    float kb = dtv * xiv;
    const float* bc = &sBC[s*32];
    sdt += dtv;
    #pragma unroll
    for (int n = 0; n < 16; ++n) {
      float da = __expf(dtv * Adn[n]);
      h[n] = da * h[n] + kb * bc[n];
    }
  }
  size_t idx = (((size_t)c * Bz + b) * NDH + d) * 16;
  #pragma unroll
  for (int n = 0; n < 16; ++n) { P[idx+n] = __expf(sdt * Adn[n]); R[idx+n] = h[n]; }
}
__global__ __launch_bounds__(256) void k_scan2(const float* __restrict__ P, const float* __restrict__ R,
                                               float* __restrict__ Hin){
  int i = blockIdx.x * 256 + threadIdx.x;   // [0, Bz*NDH*16)
  float h = 0.f;
  #pragma unroll 4
  for (int c = 0; c < NCH2; ++c) {
    size_t idx = (size_t)c * (Bz * NDH * 16) + i;
    Hin[idx] = h;
    h = P[idx] * h + R[idx];
  }
}
__global__ __launch_bounds__(256) void k_scan3r(const float* __restrict__ dtf,
                                                const bf16* __restrict__ xih, const bf16* __restrict__ xil,
                                                const float* __restrict__ xdf, const float* __restrict__ resf,
                                                const float* __restrict__ A_log, const float* __restrict__ Dsk,
                                                const float* __restrict__ Hin,
                                                bf16* __restrict__ yh, bf16* __restrict__ yl){
  int b = blockIdx.y, c = blockIdx.z;
  int d = blockIdx.x * 256 + threadIdx.x;
  __shared__ float sBC[CL2*32];
  int s0 = c * CL2;
  for (int i = threadIdx.x; i < CL2*32; i += 256)
    sBC[i] = xdf[((size_t)b*Sz + s0 + (i >> 5)) * 32 + (i & 31)];
  float Adn[16];
  #pragma unroll
  for (int n = 0; n < 16; ++n) Adn[n] = -__expf(A_log[d*16+n]);
  float Dv = Dsk[d];
  __syncthreads();
  float h[16];
  size_t hidx = (((size_t)c * Bz + b) * NDH + d) * 16;
  #pragma unroll
  for (int n = 0; n < 16; ++n) h[n] = Hin[hidx+n];
  for (int s = 0; s < CL2; ++s) {
    size_t row = (size_t)b * Sz + s0 + s;
    float dtv = dtf[row * NDH + d];
    float xiv = rc(xih, xil, row * DIz + d);
    float kb = dtv * xiv;
    const float* bc = &sBC[s*32];
    float acc = 0.f;
    #pragma unroll
    for (int n = 0; n < 16; ++n) {
      float da = __expf(dtv * Adn[n]);
      h[n] = da * h[n] + kb * bc[n];
      acc = fmaf(h[n], bc[16+n], acc);
    }
    float resv = resf[row * DIz + d];
    float yv = (acc + xiv * Dv) * (resv / (1.f + __expf(-resv)));
    split2(yv, yh[row * NDH + d], yl[row * NDH + d]);
  }
}

// ---------------- MoE gate: inline fp32 rmsnorm + scores + softmax + top-2 ----------------
__global__ __launch_bounds__(64) void k_gate(const float* __restrict__ m, const float* __restrict__ nw,
                                             const float* __restrict__ gw, const float* __restrict__ gb,
                                             int* __restrict__ topi, float* __restrict__ topw,
                                             int* __restrict__ counts){
  int t = blockIdx.x;
  int lane = threadIdx.x;
  const float* xr = m + (size_t)t * Dz;
  float xv[16];
  float ss = 0.f;
  #pragma unroll
  for (int j = 0; j < 16; ++j) { xv[j] = xr[lane + j * 64]; ss += xv[j] * xv[j]; }
  #pragma unroll
  for (int o = 32; o; o >>= 1) ss += __shfl_xor(ss, o);
  float sc = rsqrtf(ss * (1.f / Dz) + 1e-6f);
  #pragma unroll
  for (int j = 0; j < 16; ++j) xv[j] *= sc * nw[lane + j * 64];
  float acc[8] = {0.f,0.f,0.f,0.f,0.f,0.f,0.f,0.f};
  #pragma unroll
  for (int j = 0; j < 16; ++j) {
    #pragma unroll
    for (int e = 0; e < 8; ++e) acc[e] += xv[j] * gw[e * Dz + lane + j * 64];
  }
  #pragma unroll
  for (int e = 0; e < 8; ++e) {
    float v = acc[e];
    #pragma unroll
    for (int o = 32; o; o >>= 1) v += __shfl_xor(v, o);
    acc[e] = v;
  }
  if (lane == 0) {
    float mx = acc[0];
    #pragma unroll
    for (int e = 1; e < 8; ++e) mx = fmaxf(mx, acc[e]);
    float scr[8]; float sum = 0.f;
    #pragma unroll
    for (int e = 0; e < 8; ++e) { scr[e] = expf(acc[e] - mx); sum += scr[e]; }
    float inv = 1.f / sum;
    #pragma unroll
    for (int e = 0; e < 8; ++e) scr[e] *= inv;
    int i0 = 0; float b0 = -1e30f;
    #pragma unroll
    for (int e = 0; e < 8; ++e) { float kv = scr[e] + gb[e]; if (kv > b0) { b0 = kv; i0 = e; } }
    int i1 = -1; float b1 = -1e30f;
    #pragma unroll
    for (int e = 0; e < 8; ++e) { if (e == i0) continue; float kv = scr[e] + gb[e]; if (kv > b1) { b1 = kv; i1 = e; } }
    float w0 = scr[i0], w1 = scr[i1];
    float wn = 1.f / (w0 + w1 + 1e-9f);
    topi[t*2] = i0; topi[t*2+1] = i1;
    topw[t*2] = w0 * wn; topw[t*2+1] = w1 * wn;
    atomicAdd(&counts[i0], 1); atomicAdd(&counts[i1], 1);
  }
}

__global__ void k_offs(const int* __restrict__ counts, int* __restrict__ offs, int* __restrict__ fill){
  if (threadIdx.x == 0) {
    int o = 0;
    for (int e = 0; e < 8; ++e) { offs[e] = o; o += ((counts[e] + 127) & ~127); }
    offs[8] = o;
  }
  if (threadIdx.x < 8) fill[threadIdx.x] = 0;
}

__global__ __launch_bounds__(256) void k_scatter(const int* __restrict__ topi, const float* __restrict__ topw,
                                                 const int* __restrict__ offs, int* __restrict__ fill,
                                                 int* __restrict__ toks, float* __restrict__ wslot,
                                                 int* __restrict__ slot_of){
  int i = blockIdx.x * 256 + threadIdx.x;
  if (i >= Tz * 2) return;
  int e = topi[i];
  int pos = atomicAdd(&fill[e], 1);
  int slot = offs[e] + pos;
  toks[slot] = i >> 1;
  wslot[slot] = topw[i];
  slot_of[i] = slot;
}

// ---------------- final combine: out = m + down0 + down1 ----------------
__global__ __launch_bounds__(256) void k_combine(const float* __restrict__ m,
                                                 const bf16* __restrict__ Hd, const int* __restrict__ slot_of,
                                                 float* __restrict__ out){
  int t = blockIdx.x;
  int ci = threadIdx.x * 4;
  int s0 = slot_of[t*2], s1 = slot_of[t*2+1];
  size_t base = (size_t)t * Dz + ci;
  float4 mv = *(const float4*)(m + base);
  ushort4 h0 = *(const ushort4*)((const unsigned short*)Hd + (size_t)s0 * Dz + ci);
  ushort4 h1 = *(const ushort4*)((const unsigned short*)Hd + (size_t)s1 * Dz + ci);
  out[base+0] = mv.x + us2f(h0.x) + us2f(h1.x);
  out[base+1] = mv.y + us2f(h0.y) + us2f(h1.y);
  out[base+2] = mv.z + us2f(h0.z) + us2f(h1.z);
  out[base+3] = mv.w + us2f(h0.w) + us2f(h1.w);
}

extern "C" void kernel_launch(void* const* d_in, const int* in_sizes, int n_in,
                              void* d_out, int out_size, void* d_ws, size_t ws_size,
                              hipStream_t stream) {
  (void)in_sizes; (void)n_in; (void)out_size;
  const float* x         = (const float*)d_in[0];
  const float* norm_w    = (const float*)d_in[1];
  const float* in_proj   = (const float*)d_in[2];
  const float* conv_w    = (const float*)d_in[3];
  const float* conv_b    = (const float*)d_in[4];
  const float* x_proj    = (const float*)d_in[5];
  const float* dt_proj   = (const float*)d_in[6];
  const float* dt_proj_b = (const float*)d_in[7];
  const float* A_log     = (const float*)d_in[8];
  const float* D_skip    = (const float*)d_in[9];
  const float* out_proj  = (const float*)d_in[10];
  const float* gate_w    = (const float*)d_in[11];
  const float* gate_b    = (const float*)d_in[12];
  const float* w_gate    = (const float*)d_in[13];
  const float* w_up      = (const float*)d_in[14];
  const float* w_down    = (const float*)d_in[15];
  const float* ws_gate   = (const float*)d_in[16];
  const float* ws_up     = (const float*)d_in[17];
  const float* ws_down   = (const float*)d_in[18];
  float* out = (float*)d_out;

  const size_t MB = 1024 * 1024;
  const size_t NEED = 253 * MB;
  if (ws_size < NEED) {
    k_fill<<<dim3(1), dim3(256), 0, stream>>>(out, (float)(ws_size / MB));
    fprintf(stderr, "kernel_launch: ws_size=%zu < needed=%zu\n", ws_size, NEED);
    return;
  }
  char* P = (char*)d_ws;
  // ---- phase A layout (f32 for non-MFMA tensors) ----
  float* res_f = (float*)(P + 0*MB);     // [8192,2048] f32 64MB
  bf16*  xi_h  = (bf16*)(P + 64*MB);     // [8192,2048] hi 32MB
  bf16*  xi_l  = (bf16*)(P + 96*MB);     // lo 32MB
  bf16*  xd_h  = (bf16*)(P + 128*MB);    // [8192,128] 2MB
  bf16*  xd_l  = (bf16*)(P + 130*MB);
  float* xdf   = (float*)(P + 132*MB);   // [8192,32] f32 1MB (B|C)
  bf16*  xph   = (bf16*)(P + 133*MB);
  bf16*  xpl   = (bf16*)(P + 133*MB + 512*1024);
  bf16*  dph   = (bf16*)(P + 134*MB);
  bf16*  dpl   = (bf16*)(P + 134*MB + 256*1024);
  bf16*  oph   = (bf16*)(P + 135*MB);    // 4MB
  bf16*  opl   = (bf16*)(P + 139*MB);    // 4MB
  float* dtf   = (float*)(P + 144*MB);   // [8192,1024] f32 32MB (per half)
  float* scanH = (float*)(P + 176*MB);   // [64,2,1024,16] f32 8MB
  bf16*  y_h   = (bf16*)(P + 188*MB);    // [8192,1024] 16MB (per half)
  float* scanP = (float*)(P + 192*MB);   // 8MB (overlaps y_h tail: P dead before y written... see timeline)
  float* scanR = (float*)(P + 200*MB);   // 8MB
  bf16*  y_l   = (bf16*)(P + 204*MB);    // 16MB
  float* mbuf  = (float*)(P + 220*MB);   // [8192,1024] f32 32MB (persists)
  // transients:
  bf16*  nrm_h = (bf16*)(P + 144*MB);    // 16MB (dead after in_proj; dtf overlays)
  bf16*  nrm_l = (bf16*)(P + 160*MB);
  bf16*  iph   = (bf16*)(P + 176*MB);    // 8MB (dead after in_proj; scanH overlays)
  bf16*  ipl   = (bf16*)(P + 184*MB);    // 8MB
  float* xzi_f = (float*)(P + 192*MB);   // [8192,2048] f32 64MB (dead after conv)
  // ---- phase B (MoE) overlay ----
  bf16* n2b   = (bf16*)(P + 0*MB);
  bf16* wgh   = (bf16*)(P + 16*MB);
  bf16* wuh   = (bf16*)(P + 32*MB);
  bf16* wdh   = (bf16*)(P + 48*MB);
  bf16* wsg   = (bf16*)(P + 64*MB);
  bf16* wsu   = (bf16*)(P + 68*MB);
  bf16* wsd   = (bf16*)(P + 72*MB);
  bf16* Hbuf  = (bf16*)(P + 76*MB);      // [17408,1024] 34MB
  bf16* Hd    = (bf16*)(P + 110*MB);     // 34MB
  bf16* Sh    = (bf16*)(P + 144*MB);     // [8192,2048] 32MB
  char* Rt    = P + 252*MB;
  int*   counts  = (int*)(Rt);
  int*   offsb   = (int*)(Rt + 64);
  int*   fill    = (int*)(Rt + 128);
  int*   topi    = (int*)(Rt + 1024);
  float* topw    = (float*)(Rt + 1024 + 65536);
  int*   toks    = (int*)(Rt + 1024 + 2*65536);
  float* wslot   = (float*)(Rt + 1024 + 2*65536 + 69632);
  int*   slot_of = (int*)(Rt + 1024 + 2*65536 + 2*69632);

  auto spw = [&](const float* s, bf16* dh, bf16* dl, size_t n){
    k_split<<<dim3((unsigned)((n/4 + 255)/256)), dim3(256), 0, stream>>>(s, dh, dl, (int)n);
  };
  auto cvt = [&](const float* s, bf16* d, size_t n){
    k_f2bf<<<dim3((unsigned)((n/4 + 255)/256)), dim3(256), 0, stream>>>(s, d, (int)n);
  };

  spw(in_proj,  iph, ipl, (size_t)4096*1024);
  spw(dt_proj,  dph, dpl, (size_t)2048*64);
  spw(out_proj, oph, opl, (size_t)1024*2048);
  k_split_pad<<<dim3(256), dim3(256), 0, stream>>>(x_proj, xph, xpl);

  // 1. rmsnorm(x) -> normed hi/lo
  k_rmsnorm<true><<<dim3(Tz), dim3(256), 0, stream>>>(x, norm_w, nrm_h, nrm_l);
  // 2. in_proj (split, 128-tile): f32 dual store -> xzi_f / res_f
  k_gemm_sp128<1><<<dim3(Tz/128, 4096/128), dim3(256), 0, stream>>>(
      nrm_h, nrm_l, Dz, iph, ipl, Dz, xzi_f, res_f, 0, Dz, nullptr);
  // 3. causal conv + silu -> xi hi/lo
  k_conv<<<dim3(DIz/256, Tz), dim3(256), 0, stream>>>(xzi_f, conv_w, conv_b, xi_h, xi_l);
  // 4. x_proj (split naive) -> xd hi/lo + xdf f32 (B|C)
  k_gemm_sp<6><<<dim3(Tz/64, 128/64), dim3(256), 0, stream>>>(
      xi_h, xi_l, DIz, xph, xpl, DIz, xd_h, xd_l, xdf, 128, DIz, nullptr);

  // 5-7. per d-half: dt_proj -> scan -> out_proj partial
  for (int h = 0; h < 2; ++h) {
    int d0 = h * NDH;
    k_gemm_sp<5><<<dim3(Tz/64, NDH/64), dim3(256), 0, stream>>>(
        xd_h, xd_l, 128, dph + (size_t)d0*DTRz, dpl + (size_t)d0*DTRz, DTRz,
        nullptr, nullptr, dtf, NDH, DTRz, dt_proj_b + d0);
    k_scan1r<<<dim3(NDH/256, Bz, NCH2), dim3(256), 0, stream>>>(
        dtf, xi_h + d0, xi_l + d0, xdf, A_log + (size_t)d0*DSz, scanP, scanR);
    k_scan2<<<dim3(Bz*NDH*DSz/256), dim3(256), 0, stream>>>(scanP, scanR, scanH);
    k_scan3r<<<dim3(NDH/256, Bz, NCH2), dim3(256), 0, stream>>>(
        dtf, xi_h + d0, xi_l + d0, xdf, res_f + d0, A_log + (size_t)d0*DSz,
        D_skip + d0, scanH, y_h, y_l);
    if (h == 0)
      k_gemm_sp128<3><<<dim3(Tz/128, Dz/128), dim3(256), 0, stream>>>(
          y_h, y_l, NDH, oph + d0, opl + d0, DIz, mbuf, nullptr, Dz, NDH, x);
    else
      k_gemm_sp128<4><<<dim3(Tz/128, Dz/128), dim3(256), 0, stream>>>(
          y_h, y_l, NDH, oph + d0, opl + d0, DIz, mbuf, nullptr, Dz, NDH, nullptr);
  }

  // MoE weight conversion (plain bf16)
  cvt(w_gate,   wgh, (size_t)8*1024*1024);
  cvt(w_up,     wuh, (size_t)8*1024*1024);
  cvt(w_down,   wdh, (size_t)8*1024*1024);
  cvt(ws_gate,  wsg, (size_t)2048*1024);
  cvt(ws_up,    wsu, (size_t)2048*1024);
  cvt(ws_down,  wsd, (size_t)1024*2048);
  // 8. rmsnorm(m) -> n2 bf16
  k_rmsnorm<false><<<dim3(Tz), dim3(256), 0, stream>>>(mbuf, norm_w, n2b, nullptr);
  // 9. gate + routing
  k_zero_counts<<<dim3(1), dim3(64), 0, stream>>>(counts);
  k_gate<<<dim3(Tz), dim3(64), 0, stream>>>(mbuf, norm_w, gate_w, gate_b, topi, topw, counts);
  k_offs<<<dim3(1), dim3(64), 0, stream>>>(counts, offsb, fill);
  k_scatter<<<dim3(Tz*2/256), dim3(256), 0, stream>>>(topi, topw, offsb, fill, toks, wslot, slot_of);
  // 10. routed experts
  k_glu128<true><<<dim3(SLOTCAP/128, Fz/128), dim3(256), 0, stream>>>(
      n2b, Dz, wgh, wuh, Dz, (size_t)Fz*Dz, Hbuf, Fz, Dz, offsb, toks, counts);
  k_gemm128<4,true><<<dim3(SLOTCAP/128, Dz/128), dim3(256), 0, stream>>>(
      Hbuf, Fz, wdh, Fz, (size_t)Dz*Fz, Hd, Dz, Fz, wslot, offsb, counts);
  // 11. shared expert GLU -> Sh
  k_glu128<false><<<dim3(Tz/128, FSz/128), dim3(256), 0, stream>>>(
      n2b, Dz, wsg, wsu, Dz, 0, Sh, FSz, Dz, nullptr, nullptr, nullptr);
  // 12. combine -> out = m + routed
  k_combine<<<dim3(Tz), dim3(256), 0, stream>>>(mbuf, Hd, slot_of, out);
  // 13. shared down: out += Sh @ ws_down^T
  k_gemm128<5,false><<<dim3(Tz/128, Dz/128), dim3(256), 0, stream>>>(
      Sh, FSz, wsd, FSz, 0, out, Dz, FSz, nullptr, nullptr, nullptr);
}

// Round 7
// 1512.677 us; speedup vs baseline: 2.6715x; 1.0012x over previous
//
#include <hip/hip_runtime.h>
#include <hip/hip_bf16.h>
#include <cstdio>

#define Bz 2
#define Sz 4096
#define Dz 1024
#define DIz 2048
#define DSz 16
#define DTRz 64
#define NE 8
#define Fz 1024
#define FSz 2048
#define Tz (Bz*Sz)            // 8192 tokens
#define NDH 1024              // d-half width
#define NCH2 64
#define CL2 (Sz/NCH2)         // 64
#define SLOTCAP 17408         // 136 tiles * 128

typedef __hip_bfloat16 bf16;
typedef short bf16x8 __attribute__((ext_vector_type(8)));
typedef float f32x4 __attribute__((ext_vector_type(4)));

#define MFMA(a,b,c) __builtin_amdgcn_mfma_f32_16x16x32_bf16(a,b,c,0,0,0)

__device__ __forceinline__ float b2f(bf16 v){ return __bfloat162float(v); }
__device__ __forceinline__ bf16  f2b(float v){ return __float2bfloat16(v); }
__device__ __forceinline__ float us2f(unsigned short u){
  union { unsigned int i; float f; } v; v.i = ((unsigned int)u) << 16; return v.f;
}
__device__ __forceinline__ float silu(float v){ return v / (1.f + __expf(-v)); }
__device__ __forceinline__ void split2(float v, bf16& h, bf16& l){ h = f2b(v); l = f2b(v - b2f(h)); }
__device__ __forceinline__ float rc(const bf16* __restrict__ h, const bf16* __restrict__ l, size_t i){
  return b2f(h[i]) + b2f(l[i]);
}
__device__ __forceinline__ void gload16(const bf16* g, bf16* l){
  __builtin_amdgcn_global_load_lds(
      (const __attribute__((address_space(1))) void*)g,
      (__attribute__((address_space(3))) void*)l, 16, 0, 0);
}

// ---------------- guard diagnostic ----------------
__global__ void k_fill(float* __restrict__ o, float v){ o[threadIdx.x] = v; }

// ---------------- weight conversion ----------------
__global__ __launch_bounds__(256) void k_f2bf(const float* __restrict__ s, bf16* __restrict__ d, int n){
  int i = (blockIdx.x * 256 + threadIdx.x) * 4;
  if (i + 3 < n) {
    float4 v = *(const float4*)(s + i);
    d[i] = f2b(v.x); d[i+1] = f2b(v.y); d[i+2] = f2b(v.z); d[i+3] = f2b(v.w);
  }
}
__global__ __launch_bounds__(256) void k_split(const float* __restrict__ s, bf16* __restrict__ dh,
                                               bf16* __restrict__ dl, int n){
  int i = (blockIdx.x * 256 + threadIdx.x) * 4;
  if (i + 3 < n) {
    float4 v = *(const float4*)(s + i);
    split2(v.x, dh[i],   dl[i]);
    split2(v.y, dh[i+1], dl[i+1]);
    split2(v.z, dh[i+2], dl[i+2]);
    split2(v.w, dh[i+3], dl[i+3]);
  }
}
// x_proj [96,2048] -> padded [128,2048] hi/lo (pad rows = 0)
__global__ __launch_bounds__(256) void k_split_pad(const float* __restrict__ s, bf16* __restrict__ dh,
                                                   bf16* __restrict__ dl){
  int i = (blockIdx.x * 256 + threadIdx.x) * 4;
  int row = i >> 11;
  if (row < 96) {
    float4 v = *(const float4*)(s + i);
    split2(v.x, dh[i],   dl[i]);
    split2(v.y, dh[i+1], dl[i+1]);
    split2(v.z, dh[i+2], dl[i+2]);
    split2(v.w, dh[i+3], dl[i+3]);
  } else {
    bf16 z = f2b(0.f);
    dh[i]=z; dh[i+1]=z; dh[i+2]=z; dh[i+3]=z;
    dl[i]=z; dl[i+1]=z; dl[i+2]=z; dl[i+3]=z;
  }
}

__global__ void k_zero_counts(int* __restrict__ c){
  if (threadIdx.x < NE) c[threadIdx.x] = 0;
}

// ---------------- rmsnorm (f32 in). HL: hi/lo out; else single bf16 out ----------------
template<bool HL>
__global__ __launch_bounds__(256) void k_rmsnorm(const float* __restrict__ x, const float* __restrict__ w,
                                                 bf16* __restrict__ oh, bf16* __restrict__ ol){
  int row = blockIdx.x;
  const float* xr = x + (size_t)row * Dz;
  int c4 = threadIdx.x * 4;
  float4 v = *(const float4*)(xr + c4);
  float ss = v.x*v.x + v.y*v.y + v.z*v.z + v.w*v.w;
  #pragma unroll
  for (int o = 32; o; o >>= 1) ss += __shfl_xor(ss, o);
  __shared__ float sred[4];
  if ((threadIdx.x & 63) == 0) sred[threadIdx.x >> 6] = ss;
  __syncthreads();
  float tot = sred[0] + sred[1] + sred[2] + sred[3];
  float sc = rsqrtf(tot * (1.f / Dz) + 1e-6f);
  float4 wv = *(const float4*)(w + c4);
  float o0 = v.x*sc*wv.x, o1 = v.y*sc*wv.y, o2 = v.z*sc*wv.z, o3 = v.w*sc*wv.w;
  size_t ci = (size_t)row * Dz + c4;
  if (HL) {
    split2(o0, oh[ci], ol[ci]);   split2(o1, oh[ci+1], ol[ci+1]);
    split2(o2, oh[ci+2], ol[ci+2]); split2(o3, oh[ci+3], ol[ci+3]);
  } else {
    oh[ci] = f2b(o0); oh[ci+1] = f2b(o1); oh[ci+2] = f2b(o2); oh[ci+3] = f2b(o3);
  }
}

// ======== naive 64x64 split GEMM for small shapes ========
// EPI 5: Cf[row*ldc+col] = softplus(v+epi[col])  (dt_proj)
// EPI 6: hi/lo store to C1h/C1l (ldc); cols [64,96) also f32 -> Cf[row*32+col-64] (x_proj)
template<int EPI>
__global__ __launch_bounds__(256) void k_gemm_sp(
    const bf16* __restrict__ Ah, const bf16* __restrict__ Al, int lda,
    const bf16* __restrict__ Bh, const bf16* __restrict__ Bl, int ldb,
    bf16* __restrict__ C1h, bf16* __restrict__ C1l,
    float* __restrict__ Cf, int ldc, int K,
    const float* __restrict__ epi)
{
  int row0 = blockIdx.x * 64;
  int lane = threadIdx.x & 63, wid = threadIdx.x >> 6;
  int m0 = row0 + (wid >> 1) * 32;
  int n0 = blockIdx.y * 64 + (wid & 1) * 32;
  int lr = lane & 15, lk = (lane >> 4) * 8;
  const bf16 *pah0 = Ah + (size_t)(m0+lr)*lda + lk, *pah1 = pah0 + (size_t)16*lda;
  const bf16 *pal0 = Al + (size_t)(m0+lr)*lda + lk, *pal1 = pal0 + (size_t)16*lda;
  const bf16 *pbh0 = Bh + (size_t)(n0+lr)*ldb + lk, *pbh1 = pbh0 + (size_t)16*ldb;
  const bf16 *pbl0 = Bl + (size_t)(n0+lr)*ldb + lk, *pbl1 = pbl0 + (size_t)16*ldb;
  f32x4 a00 = {0.f,0.f,0.f,0.f}, a01 = a00, a10 = a00, a11 = a00;
  for (int k = 0; k < K; k += 32) {
    bf16x8 AH0 = *(const bf16x8*)pah0, AH1 = *(const bf16x8*)pah1;
    bf16x8 AL0 = *(const bf16x8*)pal0, AL1 = *(const bf16x8*)pal1;
    bf16x8 BH0 = *(const bf16x8*)pbh0, BH1 = *(const bf16x8*)pbh1;
    bf16x8 BL0 = *(const bf16x8*)pbl0, BL1 = *(const bf16x8*)pbl1;
    a00 = MFMA(AH0, BH0, a00); a00 = MFMA(AH0, BL0, a00); a00 = MFMA(AL0, BH0, a00);
    a01 = MFMA(AH0, BH1, a01); a01 = MFMA(AH0, BL1, a01); a01 = MFMA(AL0, BH1, a01);
    a10 = MFMA(AH1, BH0, a10); a10 = MFMA(AH1, BL0, a10); a10 = MFMA(AL1, BH0, a10);
    a11 = MFMA(AH1, BH1, a11); a11 = MFMA(AH1, BL1, a11); a11 = MFMA(AL1, BH1, a11);
    pah0 += 32; pah1 += 32; pal0 += 32; pal1 += 32;
    pbh0 += 32; pbh1 += 32; pbl0 += 32; pbl1 += 32;
  }
  int crow = (lane >> 4) * 4, ccol = lane & 15;
  f32x4 accs[2][2] = {{a00, a01}, {a10, a11}};
  #pragma unroll
  for (int mi = 0; mi < 2; ++mi)
  #pragma unroll
  for (int ni = 0; ni < 2; ++ni)
  #pragma unroll
  for (int r = 0; r < 4; ++r) {
    int row = m0 + mi * 16 + crow + r;
    int col = n0 + ni * 16 + ccol;
    float v = accs[mi][ni][r];
    if (EPI == 5) {
      float t = v + epi[col];
      Cf[(size_t)row * ldc + col] = (t > 20.f) ? t : log1pf(__expf(t));
    } else if (EPI == 6) {
      size_t ci = (size_t)row * ldc + col;
      split2(v, C1h[ci], C1l[ci]);
      if (col >= 64 && col < 96) Cf[(size_t)row * 32 + col - 64] = v;
    }
  }
}

// ======== 128x128 LDS-staged split GEMM (3-term), T2 bank swizzle ========
// LDS tile [128][32] bf16; 16B-block index XOR'd with row&3 on BOTH stage-source and read.
// EPI 1: dual f32 store: col<2048 -> Cf, else Cf2 (inner ld 2048)   (in_proj)
// EPI 3: Cf = v + epi[ci]; EPI 4: Cf += v                           (out_proj)
template<int EPI>
__global__ __launch_bounds__(256) void k_gemm_sp128(
    const bf16* __restrict__ Ah, const bf16* __restrict__ Al, int lda,
    const bf16* __restrict__ Bh, const bf16* __restrict__ Bl, int ldb,
    float* __restrict__ Cf, float* __restrict__ Cf2, int ldc, int K,
    const float* __restrict__ epi)
{
  __shared__ __align__(16) bf16 sAh[4096], sAl[4096], sBh[4096], sBl[4096];
  int tid = threadIdx.x;
  int lane = tid & 63, w = tid >> 6;
  int row0 = blockIdx.x * 128, n00 = blockIdx.y * 128;
  int wr = (w >> 1) * 64, wc = (w & 1) * 64;
  int srow = w * 32 + (lane >> 2);
  int scol = (((lane & 3) ^ ((lane >> 2) & 3)) * 8);   // swizzled source col-block
  const bf16* pAh = Ah + (size_t)(row0 + srow) * lda + scol;
  const bf16* pAl = Al + (size_t)(row0 + srow) * lda + scol;
  const bf16* pBh = Bh + (size_t)(n00 + srow) * ldb + scol;
  const bf16* pBl = Bl + (size_t)(n00 + srow) * ldb + scol;
  int lr = lane & 15;
  int rk = (((lane >> 4) ^ (lane & 3)) * 8);           // swizzled read col-block (row&3 == lane&3)
  f32x4 acc[4][4];
  #pragma unroll
  for (int i = 0; i < 4; ++i)
    #pragma unroll
    for (int j = 0; j < 4; ++j) acc[i][j] = {0.f,0.f,0.f,0.f};
  for (int kt = 0; kt < K; kt += 32) {
    if (kt) __syncthreads();
    #pragma unroll
    for (int j = 0; j < 2; ++j) {
      int lb = (w * 128 + j * 64) * 8;
      size_t goa = (size_t)j * 16 * lda + kt;
      size_t gob = (size_t)j * 16 * ldb + kt;
      gload16(pAh + goa, &sAh[lb]);
      gload16(pAl + goa, &sAl[lb]);
      gload16(pBh + gob, &sBh[lb]);
      gload16(pBl + gob, &sBl[lb]);
    }
    __syncthreads();
    bf16x8 fa[4], fb[4], ft[4];
    #pragma unroll
    for (int i = 0; i < 4; ++i) {
      fa[i] = *(const bf16x8*)&sAh[(wr + i*16 + lr) * 32 + rk];
      fb[i] = *(const bf16x8*)&sBh[(wc + i*16 + lr) * 32 + rk];
    }
    #pragma unroll
    for (int mi = 0; mi < 4; ++mi)
      #pragma unroll
      for (int ni = 0; ni < 4; ++ni)
        acc[mi][ni] = MFMA(fa[mi], fb[ni], acc[mi][ni]);
    #pragma unroll
    for (int i = 0; i < 4; ++i) ft[i] = *(const bf16x8*)&sBl[(wc + i*16 + lr) * 32 + rk];
    #pragma unroll
    for (int mi = 0; mi < 4; ++mi)
      #pragma unroll
      for (int ni = 0; ni < 4; ++ni)
        acc[mi][ni] = MFMA(fa[mi], ft[ni], acc[mi][ni]);
    #pragma unroll
    for (int i = 0; i < 4; ++i) ft[i] = *(const bf16x8*)&sAl[(wr + i*16 + lr) * 32 + rk];
    #pragma unroll
    for (int mi = 0; mi < 4; ++mi)
      #pragma unroll
      for (int ni = 0; ni < 4; ++ni)
        acc[mi][ni] = MFMA(ft[mi], fb[ni], acc[mi][ni]);
  }
  int crow = (lane >> 4) * 4, ccol = lane & 15;
  #pragma unroll
  for (int mi = 0; mi < 4; ++mi)
  #pragma unroll
  for (int ni = 0; ni < 4; ++ni)
  #pragma unroll
  for (int r = 0; r < 4; ++r) {
    int row = row0 + wr + mi * 16 + crow + r;
    int col = n00 + wc + ni * 16 + ccol;
    float v = acc[mi][ni][r];
    if (EPI == 1) {
      size_t ci = (size_t)row * 2048 + (col & 2047);
      if (col < 2048) Cf[ci] = v; else Cf2[ci] = v;
    } else if (EPI == 3) {
      size_t ci = (size_t)row * ldc + col;
      Cf[ci] = v + epi[ci];
    } else if (EPI == 4) {
      size_t ci = (size_t)row * ldc + col;
      Cf[ci] += v;
    }
  }
}

// ======== 128x128 LDS-staged plain GEMM (T2 swizzle). EPI 4 = v*wslot[row] (guarded) -> bf16, 5 = f32 += ========
template<int EPI, bool ROUTED>
__global__ __launch_bounds__(256) void k_gemm128(
    const bf16* __restrict__ A, int lda,
    const bf16* __restrict__ Bw, int ldb, size_t estride,
    void* __restrict__ Cp, int ldc, int K,
    const float* __restrict__ epi,
    const int* __restrict__ offs, const int* __restrict__ counts)
{
  __shared__ __align__(16) bf16 sA[4096], sB[4096];
  int row0 = 0, e = 0;
  if (ROUTED) {
    int bid = blockIdx.x, cum = 0; e = -1;
    #pragma unroll
    for (int i = 0; i < 8; ++i) {
      int tiles = (offs[i+1] - offs[i]) >> 7;
      if (e < 0 && bid < cum + tiles) { e = i; row0 = offs[i] + ((bid - cum) << 7); }
      cum += tiles;
    }
    if (e < 0) return;
  } else {
    row0 = blockIdx.x * 128;
  }
  const bf16* Bm = Bw + (size_t)e * estride;
  int tid = threadIdx.x;
  int lane = tid & 63, w = tid >> 6;
  int n00 = blockIdx.y * 128;
  int wr = (w >> 1) * 64, wc = (w & 1) * 64;
  int srow = w * 32 + (lane >> 2);
  int scol = (((lane & 3) ^ ((lane >> 2) & 3)) * 8);
  const bf16* pA = A + (size_t)(row0 + srow) * lda + scol;
  const bf16* pB = Bm + (size_t)(n00 + srow) * ldb + scol;
  int lr = lane & 15;
  int rk = (((lane >> 4) ^ (lane & 3)) * 8);
  f32x4 acc[4][4];
  #pragma unroll
  for (int i = 0; i < 4; ++i)
    #pragma unroll
    for (int j = 0; j < 4; ++j) acc[i][j] = {0.f,0.f,0.f,0.f};
  for (int kt = 0; kt < K; kt += 32) {
    if (kt) __syncthreads();
    #pragma unroll
    for (int j = 0; j < 2; ++j) {
      int lb = (w * 128 + j * 64) * 8;
      gload16(pA + (size_t)j * 16 * lda + kt, &sA[lb]);
      gload16(pB + (size_t)j * 16 * ldb + kt, &sB[lb]);
    }
    __syncthreads();
    bf16x8 fa[4], fb[4];
    #pragma unroll
    for (int i = 0; i < 4; ++i) {
      fa[i] = *(const bf16x8*)&sA[(wr + i*16 + lr) * 32 + rk];
      fb[i] = *(const bf16x8*)&sB[(wc + i*16 + lr) * 32 + rk];
    }
    #pragma unroll
    for (int mi = 0; mi < 4; ++mi)
      #pragma unroll
      for (int ni = 0; ni < 4; ++ni)
        acc[mi][ni] = MFMA(fa[mi], fb[ni], acc[mi][ni]);
  }
  int crow = (lane >> 4) * 4, ccol = lane & 15;
  int base_e = ROUTED ? offs[e] : 0;
  int cnt_e  = ROUTED ? counts[e] : 0;
  #pragma unroll
  for (int mi = 0; mi < 4; ++mi)
  #pragma unroll
  for (int ni = 0; ni < 4; ++ni)
  #pragma unroll
  for (int r = 0; r < 4; ++r) {
    int row = row0 + wr + mi * 16 + crow + r;
    int col = n00 + wc + ni * 16 + ccol;
    size_t ci = (size_t)row * ldc + col;
    float v = acc[mi][ni][r];
    if (EPI == 4) {
      float wv = (row - base_e < cnt_e) ? epi[row] : 0.f;
      ((bf16*)Cp)[ci] = f2b(v * wv);
    } else if (EPI == 5) ((float*)Cp)[ci] += v;
  }
}

// ======== 128x128 LDS-staged GLU (T2 swizzle): H = silu(A@Wg^T) * (A@Wu^T), optional gather ========
template<bool ROUTED>
__global__ __launch_bounds__(256) void k_glu128(
    const bf16* __restrict__ A, int lda,
    const bf16* __restrict__ Wg, const bf16* __restrict__ Wu, int ldb, size_t estride,
    bf16* __restrict__ H, int ldc, int K,
    const int* __restrict__ offs, const int* __restrict__ toks,
    const int* __restrict__ counts)
{
  __shared__ __align__(16) bf16 sA[4096], sG[4096], sU[4096];
  int row0 = 0, e = 0;
  if (ROUTED) {
    int bid = blockIdx.x, cum = 0; e = -1;
    #pragma unroll
    for (int i = 0; i < 8; ++i) {
      int tiles = (offs[i+1] - offs[i]) >> 7;
      if (e < 0 && bid < cum + tiles) { e = i; row0 = offs[i] + ((bid - cum) << 7); }
      cum += tiles;
    }
    if (e < 0) return;
  } else {
    row0 = blockIdx.x * 128;
  }
  int tid = threadIdx.x;
  int lane = tid & 63, w = tid >> 6;
  int n00 = blockIdx.y * 128;
  int wr = (w >> 1) * 64, wc = (w & 1) * 64;
  int srow = w * 32 + (lane >> 2);
  int scol = (((lane & 3) ^ ((lane >> 2) & 3)) * 8);
  size_t arow[2];
  #pragma unroll
  for (int j = 0; j < 2; ++j) {
    int r = row0 + srow + j * 16;
    if (ROUTED) {
      int tk = toks[r];
      if (r - offs[e] >= counts[e]) tk = 0;
      tk &= (Tz - 1);
      arow[j] = (size_t)tk * lda;
    } else {
      arow[j] = (size_t)r * lda;
    }
  }
  const bf16* wg = Wg + (size_t)e * estride;
  const bf16* wu = Wu + (size_t)e * estride;
  const bf16* pG = wg + (size_t)(n00 + srow) * ldb + scol;
  const bf16* pU = wu + (size_t)(n00 + srow) * ldb + scol;
  int lr = lane & 15;
  int rk = (((lane >> 4) ^ (lane & 3)) * 8);
  f32x4 gg[4][4], uu[4][4];
  #pragma unroll
  for (int i = 0; i < 4; ++i)
    #pragma unroll
    for (int j = 0; j < 4; ++j) { gg[i][j] = {0.f,0.f,0.f,0.f}; uu[i][j] = gg[i][j]; }
  for (int kt = 0; kt < K; kt += 32) {
    if (kt) __syncthreads();
    #pragma unroll
    for (int j = 0; j < 2; ++j) {
      int lb = (w * 128 + j * 64) * 8;
      gload16(A + arow[j] + scol + kt, &sA[lb]);
      gload16(pG + (size_t)j * 16 * ldb + kt, &sG[lb]);
      gload16(pU + (size_t)j * 16 * ldb + kt, &sU[lb]);
    }
    __syncthreads();
    bf16x8 fa[4], fb[4];
    #pragma unroll
    for (int i = 0; i < 4; ++i) {
      fa[i] = *(const bf16x8*)&sA[(wr + i*16 + lr) * 32 + rk];
      fb[i] = *(const bf16x8*)&sG[(wc + i*16 + lr) * 32 + rk];
    }
    #pragma unroll
    for (int mi = 0; mi < 4; ++mi)
      #pragma unroll
      for (int ni = 0; ni < 4; ++ni)
        gg[mi][ni] = MFMA(fa[mi], fb[ni], gg[mi][ni]);
    #pragma unroll
    for (int i = 0; i < 4; ++i) fb[i] = *(const bf16x8*)&sU[(wc + i*16 + lr) * 32 + rk];
    #pragma unroll
    for (int mi = 0; mi < 4; ++mi)
      #pragma unroll
      for (int ni = 0; ni < 4; ++ni)
        uu[mi][ni] = MFMA(fa[mi], fb[ni], uu[mi][ni]);
  }
  int crow = (lane >> 4) * 4, ccol = lane & 15;
  #pragma unroll
  for (int mi = 0; mi < 4; ++mi)
  #pragma unroll
  for (int ni = 0; ni < 4; ++ni)
  #pragma unroll
  for (int r = 0; r < 4; ++r) {
    int row = row0 + wr + mi * 16 + crow + r;
    int col = n00 + wc + ni * 16 + ccol;
    float g = gg[mi][ni][r], u = uu[mi][ni][r];
    H[(size_t)row * ldc + col] = f2b(silu(g) * u);
  }
}

// ---------------- causal depthwise conv (4 taps) + silu; f32 in -> hi/lo out ----------------
__global__ __launch_bounds__(256) void k_conv(const float* __restrict__ xz,
                                              const float* __restrict__ cw, const float* __restrict__ cb,
                                              bf16* __restrict__ oh, bf16* __restrict__ ol){
  int d = blockIdx.x * 256 + threadIdx.x;   // [0,2048)
  int row = blockIdx.y;                     // [0,8192)
  int s = row & (Sz - 1);
  size_t base = (size_t)row * DIz + d;
  float w0 = cw[d*4+0], w1 = cw[d*4+1], w2 = cw[d*4+2], w3 = cw[d*4+3];
  float x0 = (s >= 3) ? xz[base - 3*DIz] : 0.f;
  float x1 = (s >= 2) ? xz[base - 2*DIz] : 0.f;
  float x2 = (s >= 1) ? xz[base - 1*DIz] : 0.f;
  float x3 = xz[base];
  float v = cb[d] + w0*x0 + w1*x1 + w2*x2 + w3*x3;
  float o = v / (1.f + __expf(-v));
  split2(o, oh[base], ol[base]);
}

// ---------------- chunked selective scan: thread-per-d, h[16] in registers ----------------
__global__ __launch_bounds__(256) void k_scan1r(const float* __restrict__ dtf,
                                                const bf16* __restrict__ xih, const bf16* __restrict__ xil,
                                                const float* __restrict__ xdf, const float* __restrict__ A_log,
                                                float* __restrict__ P, float* __restrict__ R){
  int b = blockIdx.y, c = blockIdx.z;
  int d = blockIdx.x * 256 + threadIdx.x;   // [0,NDH)
  __shared__ float sBC[CL2*32];             // 8KB
  int s0 = c * CL2;
  for (int i = threadIdx.x; i < CL2*32; i += 256)
    sBC[i] = xdf[((size_t)b*Sz + s0 + (i >> 5)) * 32 + (i & 31)];
  float Adn[16];
  #pragma unroll
  for (int n = 0; n < 16; ++n) Adn[n] = -__expf(A_log[d*16+n]);
  __syncthreads();
  float h[16];
  #pragma unroll
  for (int n = 0; n < 16; ++n) h[n] = 0.f;
  float sdt = 0.f;
  for (int s = 0; s < CL2; ++s) {
    size_t row = (size_t)b * Sz + s0 + s;
    float dtv = dtf[row * NDH + d];
    float xiv = rc(xih, xil, row * DIz + d);
    float kb = dtv * xiv;
    const float* bc = &sBC[s*32];
    sdt += dtv;
    #pragma unroll
    for (int n = 0; n < 16; ++n) {
      float da = __expf(dtv * Adn[n]);
      h[n] = da * h[n] + kb * bc[n];
    }
  }
  size_t idx = (((size_t)c * Bz + b) * NDH + d) * 16;
  #pragma unroll
  for (int n = 0; n < 16; ++n) { P[idx+n] = __expf(sdt * Adn[n]); R[idx+n] = h[n]; }
}
__global__ __launch_bounds__(256) void k_scan2(const float* __restrict__ P, const float* __restrict__ R,
                                               float* __restrict__ Hin){
  int i = blockIdx.x * 256 + threadIdx.x;   // [0, Bz*NDH*16)
  float h = 0.f;
  #pragma unroll 4
  for (int c = 0; c < NCH2; ++c) {
    size_t idx = (size_t)c * (Bz * NDH * 16) + i;
    Hin[idx] = h;
    h = P[idx] * h + R[idx];
  }
}
__global__ __launch_bounds__(256) void k_scan3r(const float* __restrict__ dtf,
                                                const bf16* __restrict__ xih, const bf16* __restrict__ xil,
                                                const float* __restrict__ xdf, const float* __restrict__ resf,
                                                const float* __restrict__ A_log, const float* __restrict__ Dsk,
                                                const float* __restrict__ Hin,
                                                bf16* __restrict__ yh, bf16* __restrict__ yl){
  int b = blockIdx.y, c = blockIdx.z;
  int d = blockIdx.x * 256 + threadIdx.x;
  __shared__ float sBC[CL2*32];
  int s0 = c * CL2;
  for (int i = threadIdx.x; i < CL2*32; i += 256)
    sBC[i] = xdf[((size_t)b*Sz + s0 + (i >> 5)) * 32 + (i & 31)];
  float Adn[16];
  #pragma unroll
  for (int n = 0; n < 16; ++n) Adn[n] = -__expf(A_log[d*16+n]);
  float Dv = Dsk[d];
  __syncthreads();
  float h[16];
  size_t hidx = (((size_t)c * Bz + b) * NDH + d) * 16;
  #pragma unroll
  for (int n = 0; n < 16; ++n) h[n] = Hin[hidx+n];
  for (int s = 0; s < CL2; ++s) {
    size_t row = (size_t)b * Sz + s0 + s;
    float dtv = dtf[row * NDH + d];
    float xiv = rc(xih, xil, row * DIz + d);
    float kb = dtv * xiv;
    const float* bc = &sBC[s*32];
    float acc = 0.f;
    #pragma unroll
    for (int n = 0; n < 16; ++n) {
      float da = __expf(dtv * Adn[n]);
      h[n] = da * h[n] + kb * bc[n];
      acc = fmaf(h[n], bc[16+n], acc);
    }
    float resv = resf[row * DIz + d];
    float yv = (acc + xiv * Dv) * (resv / (1.f + __expf(-resv)));
    split2(yv, yh[row * NDH + d], yl[row * NDH + d]);
  }
}

// ---------------- MoE gate: inline fp32 rmsnorm + scores + softmax + top-2 ----------------
__global__ __launch_bounds__(64) void k_gate(const float* __restrict__ m, const float* __restrict__ nw,
                                             const float* __restrict__ gw, const float* __restrict__ gb,
                                             int* __restrict__ topi, float* __restrict__ topw,
                                             int* __restrict__ counts){
  int t = blockIdx.x;
  int lane = threadIdx.x;
  const float* xr = m + (size_t)t * Dz;
  float xv[16];
  float ss = 0.f;
  #pragma unroll
  for (int j = 0; j < 16; ++j) { xv[j] = xr[lane + j * 64]; ss += xv[j] * xv[j]; }
  #pragma unroll
  for (int o = 32; o; o >>= 1) ss += __shfl_xor(ss, o);
  float sc = rsqrtf(ss * (1.f / Dz) + 1e-6f);
  #pragma unroll
  for (int j = 0; j < 16; ++j) xv[j] *= sc * nw[lane + j * 64];
  float acc[8] = {0.f,0.f,0.f,0.f,0.f,0.f,0.f,0.f};
  #pragma unroll
  for (int j = 0; j < 16; ++j) {
    #pragma unroll
    for (int e = 0; e < 8; ++e) acc[e] += xv[j] * gw[e * Dz + lane + j * 64];
  }
  #pragma unroll
  for (int e = 0; e < 8; ++e) {
    float v = acc[e];
    #pragma unroll
    for (int o = 32; o; o >>= 1) v += __shfl_xor(v, o);
    acc[e] = v;
  }
  if (lane == 0) {
    float mx = acc[0];
    #pragma unroll
    for (int e = 1; e < 8; ++e) mx = fmaxf(mx, acc[e]);
    float scr[8]; float sum = 0.f;
    #pragma unroll
    for (int e = 0; e < 8; ++e) { scr[e] = expf(acc[e] - mx); sum += scr[e]; }
    float inv = 1.f / sum;
    #pragma unroll
    for (int e = 0; e < 8; ++e) scr[e] *= inv;
    int i0 = 0; float b0 = -1e30f;
    #pragma unroll
    for (int e = 0; e < 8; ++e) { float kv = scr[e] + gb[e]; if (kv > b0) { b0 = kv; i0 = e; } }
    int i1 = -1; float b1 = -1e30f;
    #pragma unroll
    for (int e = 0; e < 8; ++e) { if (e == i0) continue; float kv = scr[e] + gb[e]; if (kv > b1) { b1 = kv; i1 = e; } }
    float w0 = scr[i0], w1 = scr[i1];
    float wn = 1.f / (w0 + w1 + 1e-9f);
    topi[t*2] = i0; topi[t*2+1] = i1;
    topw[t*2] = w0 * wn; topw[t*2+1] = w1 * wn;
    atomicAdd(&counts[i0], 1); atomicAdd(&counts[i1], 1);
  }
}

__global__ void k_offs(const int* __restrict__ counts, int* __restrict__ offs, int* __restrict__ fill){
  if (threadIdx.x == 0) {
    int o = 0;
    for (int e = 0; e < 8; ++e) { offs[e] = o; o += ((counts[e] + 127) & ~127); }
    offs[8] = o;
  }
  if (threadIdx.x < 8) fill[threadIdx.x] = 0;
}

__global__ __launch_bounds__(256) void k_scatter(const int* __restrict__ topi, const float* __restrict__ topw,
                                                 const int* __restrict__ offs, int* __restrict__ fill,
                                                 int* __restrict__ toks, float* __restrict__ wslot,
                                                 int* __restrict__ slot_of){
  int i = blockIdx.x * 256 + threadIdx.x;
  if (i >= Tz * 2) return;
  int e = topi[i];
  int pos = atomicAdd(&fill[e], 1);
  int slot = offs[e] + pos;
  toks[slot] = i >> 1;
  wslot[slot] = topw[i];
  slot_of[i] = slot;
}

// ---------------- final combine: out = m + down0 + down1 ----------------
__global__ __launch_bounds__(256) void k_combine(const float* __restrict__ m,
                                                 const bf16* __restrict__ Hd, const int* __restrict__ slot_of,
                                                 float* __restrict__ out){
  int t = blockIdx.x;
  int ci = threadIdx.x * 4;
  int s0 = slot_of[t*2], s1 = slot_of[t*2+1];
  size_t base = (size_t)t * Dz + ci;
  float4 mv = *(const float4*)(m + base);
  ushort4 h0 = *(const ushort4*)((const unsigned short*)Hd + (size_t)s0 * Dz + ci);
  ushort4 h1 = *(const ushort4*)((const unsigned short*)Hd + (size_t)s1 * Dz + ci);
  out[base+0] = mv.x + us2f(h0.x) + us2f(h1.x);
  out[base+1] = mv.y + us2f(h0.y) + us2f(h1.y);
  out[base+2] = mv.z + us2f(h0.z) + us2f(h1.z);
  out[base+3] = mv.w + us2f(h0.w) + us2f(h1.w);
}

extern "C" void kernel_launch(void* const* d_in, const int* in_sizes, int n_in,
                              void* d_out, int out_size, void* d_ws, size_t ws_size,
                              hipStream_t stream) {
  (void)in_sizes; (void)n_in; (void)out_size;
  const float* x         = (const float*)d_in[0];
  const float* norm_w    = (const float*)d_in[1];
  const float* in_proj   = (const float*)d_in[2];
  const float* conv_w    = (const float*)d_in[3];
  const float* conv_b    = (const float*)d_in[4];
  const float* x_proj    = (const float*)d_in[5];
  const float* dt_proj   = (const float*)d_in[6];
  const float* dt_proj_b = (const float*)d_in[7];
  const float* A_log     = (const float*)d_in[8];
  const float* D_skip    = (const float*)d_in[9];
  const float* out_proj  = (const float*)d_in[10];
  const float* gate_w    = (const float*)d_in[11];
  const float* gate_b    = (const float*)d_in[12];
  const float* w_gate    = (const float*)d_in[13];
  const float* w_up      = (const float*)d_in[14];
  const float* w_down    = (const float*)d_in[15];
  const float* ws_gate   = (const float*)d_in[16];
  const float* ws_up     = (const float*)d_in[17];
  const float* ws_down   = (const float*)d_in[18];
  float* out = (float*)d_out;

  const size_t MB = 1024 * 1024;
  const size_t NEED = 253 * MB;
  if (ws_size < NEED) {
    k_fill<<<dim3(1), dim3(256), 0, stream>>>(out, (float)(ws_size / MB));
    fprintf(stderr, "kernel_launch: ws_size=%zu < needed=%zu\n", ws_size, NEED);
    return;
  }
  char* P = (char*)d_ws;
  // ---- phase A layout (f32 for non-MFMA tensors) ----
  float* res_f = (float*)(P + 0*MB);     // [8192,2048] f32 64MB
  bf16*  xi_h  = (bf16*)(P + 64*MB);     // [8192,2048] hi 32MB
  bf16*  xi_l  = (bf16*)(P + 96*MB);     // lo 32MB
  bf16*  xd_h  = (bf16*)(P + 128*MB);    // [8192,128] 2MB
  bf16*  xd_l  = (bf16*)(P + 130*MB);
  float* xdf   = (float*)(P + 132*MB);   // [8192,32] f32 1MB (B|C)
  bf16*  xph   = (bf16*)(P + 133*MB);
  bf16*  xpl   = (bf16*)(P + 133*MB + 512*1024);
  bf16*  dph   = (bf16*)(P + 134*MB);
  bf16*  dpl   = (bf16*)(P + 134*MB + 256*1024);
  bf16*  oph   = (bf16*)(P + 135*MB);    // 4MB
  bf16*  opl   = (bf16*)(P + 139*MB);    // 4MB
  float* dtf   = (float*)(P + 144*MB);   // [8192,1024] f32 32MB (per half)
  float* scanH = (float*)(P + 176*MB);   // [64,2,1024,16] f32 8MB
  bf16*  y_h   = (bf16*)(P + 188*MB);    // [8192,1024] 16MB (per half)
  float* scanP = (float*)(P + 192*MB);   // 8MB
  float* scanR = (float*)(P + 200*MB);   // 8MB
  bf16*  y_l   = (bf16*)(P + 204*MB);    // 16MB
  float* mbuf  = (float*)(P + 220*MB);   // [8192,1024] f32 32MB (persists)
  // transients:
  bf16*  nrm_h = (bf16*)(P + 144*MB);    // 16MB (dead after in_proj; dtf overlays)
  bf16*  nrm_l = (bf16*)(P + 160*MB);
  bf16*  iph   = (bf16*)(P + 176*MB);    // 8MB (dead after in_proj; scanH overlays)
  bf16*  ipl   = (bf16*)(P + 184*MB);    // 8MB
  float* xzi_f = (float*)(P + 192*MB);   // [8192,2048] f32 64MB (dead after conv)
  // ---- phase B (MoE) overlay ----
  bf16* n2b   = (bf16*)(P + 0*MB);
  bf16* wgh   = (bf16*)(P + 16*MB);
  bf16* wuh   = (bf16*)(P + 32*MB);
  bf16* wdh   = (bf16*)(P + 48*MB);
  bf16* wsg   = (bf16*)(P + 64*MB);
  bf16* wsu   = (bf16*)(P + 68*MB);
  bf16* wsd   = (bf16*)(P + 72*MB);
  bf16* Hbuf  = (bf16*)(P + 76*MB);      // [17408,1024] 34MB
  bf16* Hd    = (bf16*)(P + 110*MB);     // 34MB
  bf16* Sh    = (bf16*)(P + 144*MB);     // [8192,2048] 32MB
  char* Rt    = P + 252*MB;
  int*   counts  = (int*)(Rt);
  int*   offsb   = (int*)(Rt + 64);
  int*   fill    = (int*)(Rt + 128);
  int*   topi    = (int*)(Rt + 1024);
  float* topw    = (float*)(Rt + 1024 + 65536);
  int*   toks    = (int*)(Rt + 1024 + 2*65536);
  float* wslot   = (float*)(Rt + 1024 + 2*65536 + 69632);
  int*   slot_of = (int*)(Rt + 1024 + 2*65536 + 2*69632);

  auto spw = [&](const float* s, bf16* dh, bf16* dl, size_t n){
    k_split<<<dim3((unsigned)((n/4 + 255)/256)), dim3(256), 0, stream>>>(s, dh, dl, (int)n);
  };
  auto cvt = [&](const float* s, bf16* d, size_t n){
    k_f2bf<<<dim3((unsigned)((n/4 + 255)/256)), dim3(256), 0, stream>>>(s, d, (int)n);
  };

  spw(in_proj,  iph, ipl, (size_t)4096*1024);
  spw(dt_proj,  dph, dpl, (size_t)2048*64);
  spw(out_proj, oph, opl, (size_t)1024*2048);
  k_split_pad<<<dim3(256), dim3(256), 0, stream>>>(x_proj, xph, xpl);

  // 1. rmsnorm(x) -> normed hi/lo
  k_rmsnorm<true><<<dim3(Tz), dim3(256), 0, stream>>>(x, norm_w, nrm_h, nrm_l);
  // 2. in_proj (split, 128-tile): f32 dual store -> xzi_f / res_f
  k_gemm_sp128<1><<<dim3(Tz/128, 4096/128), dim3(256), 0, stream>>>(
      nrm_h, nrm_l, Dz, iph, ipl, Dz, xzi_f, res_f, 0, Dz, nullptr);
  // 3. causal conv + silu -> xi hi/lo
  k_conv<<<dim3(DIz/256, Tz), dim3(256), 0, stream>>>(xzi_f, conv_w, conv_b, xi_h, xi_l);
  // 4. x_proj (split naive) -> xd hi/lo + xdf f32 (B|C)
  k_gemm_sp<6><<<dim3(Tz/64, 128/64), dim3(256), 0, stream>>>(
      xi_h, xi_l, DIz, xph, xpl, DIz, xd_h, xd_l, xdf, 128, DIz, nullptr);

  // 5-7. per d-half: dt_proj -> scan -> out_proj partial
  for (int h = 0; h < 2; ++h) {
    int d0 = h * NDH;
    k_gemm_sp<5><<<dim3(Tz/64, NDH/64), dim3(256), 0, stream>>>(
        xd_h, xd_l, 128, dph + (size_t)d0*DTRz, dpl + (size_t)d0*DTRz, DTRz,
        nullptr, nullptr, dtf, NDH, DTRz, dt_proj_b + d0);
    k_scan1r<<<dim3(NDH/256, Bz, NCH2), dim3(256), 0, stream>>>(
        dtf, xi_h + d0, xi_l + d0, xdf, A_log + (size_t)d0*DSz, scanP, scanR);
    k_scan2<<<dim3(Bz*NDH*DSz/256), dim3(256), 0, stream>>>(scanP, scanR, scanH);
    k_scan3r<<<dim3(NDH/256, Bz, NCH2), dim3(256), 0, stream>>>(
        dtf, xi_h + d0, xi_l + d0, xdf, res_f + d0, A_log + (size_t)d0*DSz,
        D_skip + d0, scanH, y_h, y_l);
    if (h == 0)
      k_gemm_sp128<3><<<dim3(Tz/128, Dz/128), dim3(256), 0, stream>>>(
          y_h, y_l, NDH, oph + d0, opl + d0, DIz, mbuf, nullptr, Dz, NDH, x);
    else
      k_gemm_sp128<4><<<dim3(Tz/128, Dz/128), dim3(256), 0, stream>>>(
          y_h, y_l, NDH, oph + d0, opl + d0, DIz, mbuf, nullptr, Dz, NDH, nullptr);
  }

  // MoE weight conversion (plain bf16)
  cvt(w_gate,   wgh, (size_t)8*1024*1024);
  cvt(w_up,     wuh, (size_t)8*1024*1024);
  cvt(w_down,   wdh, (size_t)8*1024*1024);
  cvt(ws_gate,  wsg, (size_t)2048*1024);
  cvt(ws_up,    wsu, (size_t)2048*1024);
  cvt(ws_down,  wsd, (size_t)1024*2048);
  // 8. rmsnorm(m) -> n2 bf16
  k_rmsnorm<false><<<dim3(Tz), dim3(256), 0, stream>>>(mbuf, norm_w, n2b, nullptr);
  // 9. gate + routing
  k_zero_counts<<<dim3(1), dim3(64), 0, stream>>>(counts);
  k_gate<<<dim3(Tz), dim3(64), 0, stream>>>(mbuf, norm_w, gate_w, gate_b, topi, topw, counts);
  k_offs<<<dim3(1), dim3(64), 0, stream>>>(counts, offsb, fill);
  k_scatter<<<dim3(Tz*2/256), dim3(256), 0, stream>>>(topi, topw, offsb, fill, toks, wslot, slot_of);
  // 10. routed experts
  k_glu128<true><<<dim3(SLOTCAP/128, Fz/128), dim3(256), 0, stream>>>(
      n2b, Dz, wgh, wuh, Dz, (size_t)Fz*Dz, Hbuf, Fz, Dz, offsb, toks, counts);
  k_gemm128<4,true><<<dim3(SLOTCAP/128, Dz/128), dim3(256), 0, stream>>>(
      Hbuf, Fz, wdh, Fz, (size_t)Dz*Fz, Hd, Dz, Fz, wslot, offsb, counts);
  // 11. shared expert GLU -> Sh
  k_glu128<false><<<dim3(Tz/128, FSz/128), dim3(256), 0, stream>>>(
      n2b, Dz, wsg, wsu, Dz, 0, Sh, FSz, Dz, nullptr, nullptr, nullptr);
  // 12. combine -> out = m + routed
  k_combine<<<dim3(Tz), dim3(256), 0, stream>>>(mbuf, Hd, slot_of, out);
  // 13. shared down: out += Sh @ ws_down^T
  k_gemm128<5,false><<<dim3(Tz/128, Dz/128), dim3(256), 0, stream>>>(
      Sh, FSz, wsd, FSz, 0, out, Dz, FSz, nullptr, nullptr, nullptr);
}